// Round 9
// baseline (588.774 us; speedup 1.0000x reference)
//
#include <hip/hip_runtime.h>

#define N_NODES  200000
#define N_EDGES  3200000
#define HIDDEN   64
#define N_GRAPHS 4096
#define N_CLASSES 7
#define NBUCK    196          // ceil(N_NODES / 1024)
#define BSHIFT   10
#define BMASK    1023
#define CPW      8            // nodes (chunk) per wave
#define NCHUNK   (N_NODES / CPW)          // 25000
#define GLAYER   (NCHUNK / 4)             // 6250 blocks of 4 waves

// ---------- coarse histogram (196 buckets) ----------
#define CH_EPT 16
__global__ void k_chist(const int* __restrict__ dst, int* __restrict__ chist) {
    __shared__ int h[NBUCK];
    for (int i = threadIdx.x; i < NBUCK; i += 256) h[i] = 0;
    __syncthreads();
    int base = blockIdx.x * 256 * CH_EPT + threadIdx.x;
    for (int k = 0; k < CH_EPT; ++k) {
        int e = base + k * 256;
        if (e < N_EDGES) atomicAdd(&h[dst[e] >> BSHIFT], 1);
    }
    __syncthreads();
    for (int i = threadIdx.x; i < NBUCK; i += 256) atomicAdd(&chist[i], h[i]);
}

// ---------- scan of 196 bucket counts ----------
__global__ void k_cscan(const int* __restrict__ chist, int* __restrict__ cbase,
                        int* __restrict__ gcur) {
    __shared__ int tmp[256];
    int tid = threadIdx.x;
    int v = (tid < NBUCK) ? chist[tid] : 0;
    int x = v; tmp[tid] = x; __syncthreads();
    for (int o = 1; o < 256; o <<= 1) {
        int y = (tid >= o) ? tmp[tid - o] : 0;
        __syncthreads();
        x += y; tmp[tid] = x;
        __syncthreads();
    }
    if (tid < NBUCK) { cbase[tid] = x - v; gcur[tid] = x - v; }
    if (tid == 0) cbase[NBUCK] = N_EDGES;
}

// ---------- coarse partition: stage[pos] = (src<<10)|(dst&1023) ----------
#define PT_EPT 32
__global__ void k_part(const int* __restrict__ src, const int* __restrict__ dst,
                       int* __restrict__ gcur, int* __restrict__ stage) {
    __shared__ int lh[NBUCK];
    __shared__ int lbase[NBUCK];
    __shared__ int lcur[NBUCK];
    for (int i = threadIdx.x; i < NBUCK; i += 256) { lh[i] = 0; lcur[i] = 0; }
    __syncthreads();
    int base = blockIdx.x * 256 * PT_EPT + threadIdx.x;
    for (int k = 0; k < PT_EPT; ++k) {
        int e = base + k * 256;
        if (e < N_EDGES) atomicAdd(&lh[dst[e] >> BSHIFT], 1);
    }
    __syncthreads();
    for (int i = threadIdx.x; i < NBUCK; i += 256)
        if (lh[i] > 0) lbase[i] = atomicAdd(&gcur[i], lh[i]);
    __syncthreads();
    for (int k = 0; k < PT_EPT; ++k) {
        int e = base + k * 256;
        if (e < N_EDGES) {
            int d = dst[e], b = d >> BSHIFT;
            int lp = atomicAdd(&lcur[b], 1);
            stage[lbase[b] + lp] = (src[e] << BSHIFT) | (d & BMASK);
        }
    }
}

// ---------- per-bucket exact sort + CSR metadata; also prescale x by dinv ----------
__global__ void k_sort(const int* __restrict__ stage, const int* __restrict__ cbase,
                       int* __restrict__ edges, int* __restrict__ off,
                       int* __restrict__ endv, float* __restrict__ dinv,
                       const float2* __restrict__ x2, float2* __restrict__ xs2) {
    __shared__ int hist[1024];
    __shared__ int tmp[256];
    int b = blockIdx.x, tid = threadIdx.x;
    int cb0 = cbase[b], cb1 = cbase[b + 1];
    for (int k = 0; k < 4; ++k) hist[tid * 4 + k] = 0;
    __syncthreads();
    for (int j = cb0 + tid; j < cb1; j += 256)
        atomicAdd(&hist[stage[j] & BMASK], 1);
    __syncthreads();
    int c0 = hist[tid*4], c1 = hist[tid*4+1], c2 = hist[tid*4+2], c3 = hist[tid*4+3];
    int s = c0 + c1 + c2 + c3;
    int x = s; tmp[tid] = x; __syncthreads();
    for (int o = 1; o < 256; o <<= 1) {
        int y = (tid >= o) ? tmp[tid - o] : 0;
        __syncthreads();
        x += y; tmp[tid] = x;
        __syncthreads();
    }
    int run = x - s;                 // exclusive prefix of this thread's 4 counters
    int nbase = b << BSHIFT;
    int counts[4] = {c0, c1, c2, c3};
    for (int k = 0; k < 4; ++k) {
        int v = tid * 4 + k;
        hist[v] = run;               // local cursor start
        int node = nbase + v;
        if (node < N_NODES) {
            off[node]  = cb0 + run;
            endv[node] = cb0 + run + counts[k];
            float di = rsqrtf((float)counts[k] + 1.0f);   // +1 self loop
            dinv[node] = di;
            float2 xv = x2[node];
            xs2[node] = make_float2(di * xv.x, di * xv.y);
        }
        run += counts[k];
    }
    __syncthreads();
    for (int j = cb0 + tid; j < cb1; j += 256) {
        int p = stage[j];
        int pos = atomicAdd(&hist[p & BMASK], 1);
        edges[cb0 + pos] = p >> BSHIFT;     // src
    }
}

static __device__ __forceinline__ float rdlf(float v, int l) {
    return __uint_as_float(__builtin_amdgcn_readlane(__float_as_uint(v), (unsigned)l));
}
static __device__ __forceinline__ int rdli(int v, int l) {
    return __builtin_amdgcn_readlane(v, (unsigned)l);
}

// ---------- layer 1: chunked gather of prescaled x + W1 + relu + fused W2 ----------
__global__ __launch_bounds__(256, 4)
void k_l1(const int* __restrict__ edges, const int* __restrict__ off,
          const int* __restrict__ endv, const float* __restrict__ dinv,
          const float2* __restrict__ xs2,
          const float* __restrict__ W1, const float* __restrict__ b1,
          const float* __restrict__ W2, float* __restrict__ Yout) {
    int lane = threadIdx.x & 63;
    int wid = blockIdx.x * 4 + (threadIdx.x >> 6);
    int n0 = wid * CPW;
    if (n0 >= N_NODES) return;
    float w1a = W1[lane], w1b = W1[64 + lane], bb = b1[lane];
    float4 wc[16];
#pragma unroll
    for (int t = 0; t < 16; ++t) {
        wc[t].x = W2[(4 * t + 0) * 64 + lane];
        wc[t].y = W2[(4 * t + 1) * 64 + lane];
        wc[t].z = W2[(4 * t + 2) * 64 + lane];
        wc[t].w = W2[(4 * t + 3) * 64 + lane];
    }
    // chunk metadata in lanes 0..CPW-1
    int mo = 0, me = 0; float md = 0.0f; float sxx = 0.0f, sxy = 0.0f;
    if (lane < CPW) {
        int nn = n0 + lane;
        mo = off[nn]; me = endv[nn]; md = dinv[nn];
        float2 sv = xs2[nn];
        sxx = sv.x; sxy = sv.y;
    }
    int j0 = rdli(mo, 0);
    int idx = j0 + lane; if (idx > N_EDGES - 1) idx = N_EDGES - 1;
    int ev = edges[idx];
    for (int i = 0; i < CPW; ++i) {
        int n = n0 + i;
        int j1 = rdli(me, i);
        float dn = rdlf(md, i);
        int deg = j1 - j0;
        int evn = 0; int j0n = 0;
        if (i < CPW - 1) {
            j0n = rdli(mo, i + 1);
            int idn = j0n + lane; if (idn > N_EDGES - 1) idn = N_EDGES - 1;
            evn = edges[idn];
        }
        float px = 0.0f, py = 0.0f;
        if (lane < deg) {                       // deg <= 64 (typ. ~16)
            float2 v = xs2[ev];
            px = v.x; py = v.y;
        }
        for (int jj = j0 + 64 + lane; jj < j1; jj += 64) {   // rare deg>64 tail
            float2 v = xs2[edges[jj]];
            px += v.x; py += v.y;
        }
#pragma unroll
        for (int o = 1; o < 64; o <<= 1) {
            px += __shfl_xor(px, o, 64);
            py += __shfl_xor(py, o, 64);
        }
        float gx = dn * (px + rdlf(sxx, i));
        float gy = dn * (py + rdlf(sxy, i));
        float h = gx * w1a + gy * w1b + bb;
        h = h > 0.0f ? h : 0.0f;
        float y0 = 0.0f, y1 = 0.0f, y2 = 0.0f, y3 = 0.0f;
#pragma unroll
        for (int t = 0; t < 16; ++t) {
            float4 w = wc[t];
            y0 = fmaf(rdlf(h, 4 * t + 0), w.x, y0);
            y1 = fmaf(rdlf(h, 4 * t + 1), w.y, y1);
            y2 = fmaf(rdlf(h, 4 * t + 2), w.z, y2);
            y3 = fmaf(rdlf(h, 4 * t + 3), w.w, y3);
        }
        Yout[n * 64 + lane] = dn * ((y0 + y1) + (y2 + y3));
        ev = evn; j0 = j0n;
    }
}

// ---------- layers 2/3: PAIRED quad-row gather (8+ row loads in flight) ----------
template<bool FINAL>
__global__ __launch_bounds__(256, 4)
void k_gl(const int* __restrict__ edges, const int* __restrict__ off,
          const int* __restrict__ endv, const float* __restrict__ dinv,
          const float* __restrict__ Yin, const float* __restrict__ Wn,
          const float* __restrict__ bias, float* __restrict__ Yout) {
    const float4* __restrict__ Yin4 = (const float4*)Yin;
    int lane = threadIdx.x & 63;
    int q = lane & 15, s = lane >> 4;          // sub-group: s = which row of a quad
    int wid = blockIdx.x * 4 + (threadIdx.x >> 6);
    int n0 = wid * CPW;
    if (n0 >= N_NODES) return;
    float bb = bias[lane];
    float4 wc[16];
    if (!FINAL) {
#pragma unroll
        for (int t = 0; t < 16; ++t) {
            wc[t].x = Wn[(4 * t + 0) * 64 + lane];
            wc[t].y = Wn[(4 * t + 1) * 64 + lane];
            wc[t].z = Wn[(4 * t + 2) * 64 + lane];
            wc[t].w = Wn[(4 * t + 3) * 64 + lane];
        }
    }
    // chunk metadata in lanes 0..CPW-1
    int mo = 0, me = 0; float md = 0.0f;
    if (lane < CPW) {
        int nn = n0 + lane;
        mo = off[nn]; me = endv[nn]; md = dinv[nn];
    }
    int j0a = rdli(mo, 0), j0b = rdli(mo, 1);
    int ia0 = j0a + lane; if (ia0 > N_EDGES - 1) ia0 = N_EDGES - 1;
    int ib0 = j0b + lane; if (ib0 > N_EDGES - 1) ib0 = N_EDGES - 1;
    int eva = edges[ia0], evb = edges[ib0];
    float4 sa = make_float4(0.f, 0.f, 0.f, 0.f);
    float4 sb = make_float4(0.f, 0.f, 0.f, 0.f);
    if (s == 0) {
        sa = Yin4[(size_t)(n0 + 0) * 16 + q];
        sb = Yin4[(size_t)(n0 + 1) * 16 + q];
    }
    for (int i = 0; i < CPW; i += 2) {
        int na = n0 + i, nb = na + 1;
        int j1a = rdli(me, i), j1b = rdli(me, i + 1);
        float da = rdlf(md, i), db = rdlf(md, i + 1);
        int dega = j1a - j0a, degb = j1b - j0b;
        int ma = dega < 64 ? dega : 64;
        int mb = degb < 64 ? degb : 64;
        // prefetch next pair's edge vectors + self rows
        int j0an = 0, j0bn = 0, evan = 0, evbn = 0;
        float4 san = make_float4(0.f, 0.f, 0.f, 0.f);
        float4 sbn = make_float4(0.f, 0.f, 0.f, 0.f);
        if (i + 2 < CPW) {
            j0an = rdli(mo, i + 2); j0bn = rdli(mo, i + 3);
            int ian = j0an + lane; if (ian > N_EDGES - 1) ian = N_EDGES - 1;
            int ibn = j0bn + lane; if (ibn > N_EDGES - 1) ibn = N_EDGES - 1;
            evan = edges[ian]; evbn = edges[ibn];
            if (s == 0) {
                san = Yin4[(size_t)(na + 2) * 16 + q];
                sbn = Yin4[(size_t)(nb + 2) * 16 + q];
            }
        }
        // ---- phase 1: unconditionally issue 8 quad-loads (slots 0..15 of a AND b) ----
        int xa0 = __shfl(eva, 0 + s, 64);
        int xa1 = __shfl(eva, 4 + s, 64);
        int xa2 = __shfl(eva, 8 + s, 64);
        int xa3 = __shfl(eva, 12 + s, 64);
        int xb0 = __shfl(evb, 0 + s, 64);
        int xb1 = __shfl(evb, 4 + s, 64);
        int xb2 = __shfl(evb, 8 + s, 64);
        int xb3 = __shfl(evb, 12 + s, 64);
        float4 va0 = Yin4[(size_t)xa0 * 16 + q];
        float4 va1 = Yin4[(size_t)xa1 * 16 + q];
        float4 va2 = Yin4[(size_t)xa2 * 16 + q];
        float4 va3 = Yin4[(size_t)xa3 * 16 + q];
        float4 vb0 = Yin4[(size_t)xb0 * 16 + q];
        float4 vb1 = Yin4[(size_t)xb1 * 16 + q];
        float4 vb2 = Yin4[(size_t)xb2 * 16 + q];
        float4 vb3 = Yin4[(size_t)xb3 * 16 + q];
        // ---- masked accumulate (per-lane slot < m) ----
        float4 acca = sa, accb = sb;
        if (0 + s < ma)  { acca.x += va0.x; acca.y += va0.y; acca.z += va0.z; acca.w += va0.w; }
        if (4 + s < ma)  { acca.x += va1.x; acca.y += va1.y; acca.z += va1.z; acca.w += va1.w; }
        if (8 + s < ma)  { acca.x += va2.x; acca.y += va2.y; acca.z += va2.z; acca.w += va2.w; }
        if (12 + s < ma) { acca.x += va3.x; acca.y += va3.y; acca.z += va3.z; acca.w += va3.w; }
        if (0 + s < mb)  { accb.x += vb0.x; accb.y += vb0.y; accb.z += vb0.z; accb.w += vb0.w; }
        if (4 + s < mb)  { accb.x += vb1.x; accb.y += vb1.y; accb.z += vb1.z; accb.w += vb1.w; }
        if (8 + s < mb)  { accb.x += vb2.x; accb.y += vb2.y; accb.z += vb2.z; accb.w += vb2.w; }
        if (12 + s < mb) { accb.x += vb3.x; accb.y += vb3.y; accb.z += vb3.z; accb.w += vb3.w; }
        // ---- phase 2: guarded quads for deg 17..64 ----
        int mmax = ma > mb ? ma : mb;
        for (int u = 4; 4 * u < mmax; ++u) {
            int sl = 4 * u + s;
            int xa = __shfl(eva, sl, 64);
            int xb = __shfl(evb, sl, 64);
            if (4 * u < ma) {
                float4 v = Yin4[(size_t)xa * 16 + q];
                if (sl < ma) { acca.x += v.x; acca.y += v.y; acca.z += v.z; acca.w += v.w; }
            }
            if (4 * u < mb) {
                float4 v = Yin4[(size_t)xb * 16 + q];
                if (sl < mb) { accb.x += v.x; accb.y += v.y; accb.z += v.z; accb.w += v.w; }
            }
        }
        // ---- phase 3: astronomically rare deg > 64 ----
        for (int jj = 64; jj < dega; ++jj) {
            int sidx = edges[j0a + jj];
            if (s == 0) {
                float4 v = Yin4[(size_t)sidx * 16 + q];
                acca.x += v.x; acca.y += v.y; acca.z += v.z; acca.w += v.w;
            }
        }
        for (int jj = 64; jj < degb; ++jj) {
            int sidx = edges[j0b + jj];
            if (s == 0) {
                float4 v = Yin4[(size_t)sidx * 16 + q];
                accb.x += v.x; accb.y += v.y; accb.z += v.z; accb.w += v.w;
            }
        }
        // ---- combine the 4 sub-groups (a and b interleaved for ILP) ----
        acca.x += __shfl_xor(acca.x, 16, 64); accb.x += __shfl_xor(accb.x, 16, 64);
        acca.x += __shfl_xor(acca.x, 32, 64); accb.x += __shfl_xor(accb.x, 32, 64);
        acca.y += __shfl_xor(acca.y, 16, 64); accb.y += __shfl_xor(accb.y, 16, 64);
        acca.y += __shfl_xor(acca.y, 32, 64); accb.y += __shfl_xor(accb.y, 32, 64);
        acca.z += __shfl_xor(acca.z, 16, 64); accb.z += __shfl_xor(accb.z, 16, 64);
        acca.z += __shfl_xor(acca.z, 32, 64); accb.z += __shfl_xor(accb.z, 32, 64);
        acca.w += __shfl_xor(acca.w, 16, 64); accb.w += __shfl_xor(accb.w, 16, 64);
        acca.w += __shfl_xor(acca.w, 32, 64); accb.w += __shfl_xor(accb.w, 32, 64);
        // ---- redistribute to channel-per-lane, finish, store: node a then b ----
        int srcl = lane >> 2;
        {
            float c0 = __shfl(acca.x, srcl, 64);
            float c1 = __shfl(acca.y, srcl, 64);
            float c2 = __shfl(acca.z, srcl, 64);
            float c3 = __shfl(acca.w, srcl, 64);
            float lo = (lane & 1) ? c1 : c0;
            float hi = (lane & 1) ? c3 : c2;
            float sumc = (lane & 2) ? hi : lo;
            float h = da * sumc + bb;
            h = h > 0.0f ? h : 0.0f;
            if (FINAL) {
                Yout[na * 64 + lane] = h;
            } else {
                float y0 = 0.0f, y1 = 0.0f, y2 = 0.0f, y3 = 0.0f;
#pragma unroll
                for (int t2 = 0; t2 < 16; ++t2) {
                    float4 w = wc[t2];
                    y0 = fmaf(rdlf(h, 4 * t2 + 0), w.x, y0);
                    y1 = fmaf(rdlf(h, 4 * t2 + 1), w.y, y1);
                    y2 = fmaf(rdlf(h, 4 * t2 + 2), w.z, y2);
                    y3 = fmaf(rdlf(h, 4 * t2 + 3), w.w, y3);
                }
                Yout[na * 64 + lane] = da * ((y0 + y1) + (y2 + y3));
            }
        }
        {
            float c0 = __shfl(accb.x, srcl, 64);
            float c1 = __shfl(accb.y, srcl, 64);
            float c2 = __shfl(accb.z, srcl, 64);
            float c3 = __shfl(accb.w, srcl, 64);
            float lo = (lane & 1) ? c1 : c0;
            float hi = (lane & 1) ? c3 : c2;
            float sumc = (lane & 2) ? hi : lo;
            float h = db * sumc + bb;
            h = h > 0.0f ? h : 0.0f;
            if (FINAL) {
                Yout[nb * 64 + lane] = h;
            } else {
                float y0 = 0.0f, y1 = 0.0f, y2 = 0.0f, y3 = 0.0f;
#pragma unroll
                for (int t2 = 0; t2 < 16; ++t2) {
                    float4 w = wc[t2];
                    y0 = fmaf(rdlf(h, 4 * t2 + 0), w.x, y0);
                    y1 = fmaf(rdlf(h, 4 * t2 + 1), w.y, y1);
                    y2 = fmaf(rdlf(h, 4 * t2 + 2), w.z, y2);
                    y3 = fmaf(rdlf(h, 4 * t2 + 3), w.w, y3);
                }
                Yout[nb * 64 + lane] = db * ((y0 + y1) + (y2 + y3));
            }
        }
        eva = evan; evb = evbn; sa = san; sb = sbn; j0a = j0an; j0b = j0bn;
    }
}

// ---------- segmented mean-pool accumulation (batch is sorted) ----------
#define PCHUNK 64
__global__ void k_pool(const float* __restrict__ A, const int* __restrict__ batch,
                       float* __restrict__ sums, float* __restrict__ cnts) {
    int c = threadIdx.x;
    int n0 = blockIdx.x * PCHUNK;
    int n1 = n0 + PCHUNK; if (n1 > N_NODES) n1 = N_NODES;
    int gcur = batch[n0];
    float acc = 0.0f;
    int cnt = 0;
    for (int n = n0; n < n1; ++n) {
        int g = batch[n];
        if (g != gcur) {
            atomicAdd(&sums[gcur * 64 + c], acc);
            if (c == 0) atomicAdd(&cnts[gcur], (float)cnt);
            acc = 0.0f; cnt = 0; gcur = g;
        }
        acc += A[n * 64 + c];
        ++cnt;
    }
    atomicAdd(&sums[gcur * 64 + c], acc);
    if (c == 0) atomicAdd(&cnts[gcur], (float)cnt);
}

// ---------- MLP head ----------
__global__ void k_head(const float* __restrict__ sums, const float* __restrict__ cnts,
                       const float* __restrict__ Wf1, const float* __restrict__ bf1,
                       const float* __restrict__ Wf2, const float* __restrict__ bf2,
                       float* __restrict__ out) {
    __shared__ float p[64];
    __shared__ float h[64];
    int g = blockIdx.x;
    int c = threadIdx.x;
    float cnt = cnts[g];
    cnt = cnt > 1.0f ? cnt : 1.0f;
    p[c] = sums[g * 64 + c] / cnt;
    __syncthreads();
    float s = bf1[c];
#pragma unroll
    for (int k = 0; k < 64; ++k) s += p[k] * Wf1[k * 64 + c];
    h[c] = s > 0.0f ? s : 0.0f;
    __syncthreads();
    if (c < N_CLASSES) {
        float o = bf2[c];
#pragma unroll
        for (int k = 0; k < 64; ++k) o += h[k] * Wf2[k * N_CLASSES + c];
        out[g * N_CLASSES + c] = o;
    }
}

extern "C" void kernel_launch(void* const* d_in, const int* in_sizes, int n_in,
                              void* d_out, int out_size, void* d_ws, size_t ws_size,
                              hipStream_t stream) {
    const float* x   = (const float*)d_in[0];
    const int*   ei  = (const int*)d_in[1];
    const int*   bat = (const int*)d_in[2];
    const float* W1  = (const float*)d_in[3];
    const float* b1  = (const float*)d_in[4];
    const float* W2  = (const float*)d_in[5];
    const float* b2  = (const float*)d_in[6];
    const float* W3  = (const float*)d_in[7];
    const float* b3  = (const float*)d_in[8];
    const float* Wf1 = (const float*)d_in[9];
    const float* bf1 = (const float*)d_in[10];
    const float* Wf2 = (const float*)d_in[11];
    const float* bf2 = (const float*)d_in[12];
    float* out = (float*)d_out;

    const int* src = ei;
    const int* dst = ei + N_EDGES;

    char* p = (char*)d_ws;
    float* P     = (float*)p;   p += (size_t)N_NODES * 64 * 4;
    float* Q     = (float*)p;   p += (size_t)N_NODES * 64 * 4;
    int*   stage = (int*)p;     p += (size_t)N_EDGES * 4;
    int*   edges = (int*)p;     p += (size_t)N_EDGES * 4;
    int*   off   = (int*)p;     p += (size_t)N_NODES * 4;
    int*   endv  = (int*)p;     p += (size_t)N_NODES * 4;
    float* dinv  = (float*)p;   p += (size_t)N_NODES * 4;
    float* xs2   = (float*)p;   p += (size_t)N_NODES * 2 * 4;
    int*   chist = (int*)p;     p += (size_t)256 * 4;
    int*   cbase = (int*)p;     p += (size_t)256 * 4;
    int*   gcur  = (int*)p;     p += (size_t)256 * 4;
    float* sums  = (float*)p;   p += (size_t)N_GRAPHS * 64 * 4;
    float* cnts  = (float*)p;   p += (size_t)N_GRAPHS * 4;

    hipMemsetAsync(chist, 0, 256 * 4, stream);
    hipMemsetAsync(sums, 0, (size_t)(N_GRAPHS * 64 + N_GRAPHS) * 4, stream);

    const int BT = 256;
    int gChist = (N_EDGES + 256 * CH_EPT - 1) / (256 * CH_EPT);   // 782
    int gPart  = (N_EDGES + 256 * PT_EPT - 1) / (256 * PT_EPT);   // 391

    // ---- CSR build (binned, no global scatter over full buffer) ----
    k_chist<<<gChist, BT, 0, stream>>>(dst, chist);
    k_cscan<<<1, 256, 0, stream>>>(chist, cbase, gcur);
    k_part<<<gPart, BT, 0, stream>>>(src, dst, gcur, stage);
    k_sort<<<NBUCK, 256, 0, stream>>>(stage, cbase, edges, off, endv, dinv,
                                      (const float2*)x, (float2*)xs2);

    // ---- layer 1 (gather x, W1, relu, fused W2 transform + prescale) ----
    k_l1<<<GLAYER, BT, 0, stream>>>(edges, off, endv, dinv, (const float2*)xs2,
                                    W1, b1, W2, P);

    // ---- layer 2 (paired quad gather + b2/relu + fused W3 transform + prescale) ----
    k_gl<false><<<GLAYER, BT, 0, stream>>>(edges, off, endv, dinv, P, W3, b2, Q);

    // ---- layer 3 (paired quad gather + b3/relu, final activations) ----
    k_gl<true><<<GLAYER, BT, 0, stream>>>(edges, off, endv, dinv, Q, nullptr, b3, P);

    // ---- pool + head ----
    k_pool<<<(N_NODES + PCHUNK - 1) / PCHUNK, 64, 0, stream>>>(P, bat, sums, cnts);
    k_head<<<N_GRAPHS, 64, 0, stream>>>(sums, cnts, Wf1, bf1, Wf2, bf2, out);
}

// Round 11
// 502.722 us; speedup vs baseline: 1.1712x; 1.1712x over previous
//
#include <hip/hip_runtime.h>
#include <hip/hip_fp16.h>

#define N_NODES  200000
#define N_EDGES  3200000
#define HIDDEN   64
#define N_GRAPHS 4096
#define N_CLASSES 7
#define NBUCK    196          // ceil(N_NODES / 1024)
#define BSHIFT   10
#define BMASK    1023
#define CPW      16           // nodes (chunk) per wave
#define NCHUNK   (N_NODES / CPW)          // 12500
#define GLAYER   (NCHUNK / 4)             // 3125 blocks of 4 waves

// ---------- coarse histogram (196 buckets) ----------
#define CH_EPT 16
__global__ void k_chist(const int* __restrict__ dst, int* __restrict__ chist) {
    __shared__ int h[NBUCK];
    for (int i = threadIdx.x; i < NBUCK; i += 256) h[i] = 0;
    __syncthreads();
    int base = blockIdx.x * 256 * CH_EPT + threadIdx.x;
    for (int k = 0; k < CH_EPT; ++k) {
        int e = base + k * 256;
        if (e < N_EDGES) atomicAdd(&h[dst[e] >> BSHIFT], 1);
    }
    __syncthreads();
    for (int i = threadIdx.x; i < NBUCK; i += 256) atomicAdd(&chist[i], h[i]);
}

// ---------- scan of 196 bucket counts ----------
__global__ void k_cscan(const int* __restrict__ chist, int* __restrict__ cbase,
                        int* __restrict__ gcur) {
    __shared__ int tmp[256];
    int tid = threadIdx.x;
    int v = (tid < NBUCK) ? chist[tid] : 0;
    int x = v; tmp[tid] = x; __syncthreads();
    for (int o = 1; o < 256; o <<= 1) {
        int y = (tid >= o) ? tmp[tid - o] : 0;
        __syncthreads();
        x += y; tmp[tid] = x;
        __syncthreads();
    }
    if (tid < NBUCK) { cbase[tid] = x - v; gcur[tid] = x - v; }
    if (tid == 0) cbase[NBUCK] = N_EDGES;
}

// ---------- coarse partition: stage[pos] = (src<<10)|(dst&1023) ----------
#define PT_EPT 32
__global__ void k_part(const int* __restrict__ src, const int* __restrict__ dst,
                       int* __restrict__ gcur, int* __restrict__ stage) {
    __shared__ int lh[NBUCK];
    __shared__ int lbase[NBUCK];
    __shared__ int lcur[NBUCK];
    for (int i = threadIdx.x; i < NBUCK; i += 256) { lh[i] = 0; lcur[i] = 0; }
    __syncthreads();
    int base = blockIdx.x * 256 * PT_EPT + threadIdx.x;
    for (int k = 0; k < PT_EPT; ++k) {
        int e = base + k * 256;
        if (e < N_EDGES) atomicAdd(&lh[dst[e] >> BSHIFT], 1);
    }
    __syncthreads();
    for (int i = threadIdx.x; i < NBUCK; i += 256)
        if (lh[i] > 0) lbase[i] = atomicAdd(&gcur[i], lh[i]);
    __syncthreads();
    for (int k = 0; k < PT_EPT; ++k) {
        int e = base + k * 256;
        if (e < N_EDGES) {
            int d = dst[e], b = d >> BSHIFT;
            int lp = atomicAdd(&lcur[b], 1);
            stage[lbase[b] + lp] = (src[e] << BSHIFT) | (d & BMASK);
        }
    }
}

// ---------- per-bucket exact sort + CSR metadata; also prescale x by dinv ----------
__global__ void k_sort(const int* __restrict__ stage, const int* __restrict__ cbase,
                       int* __restrict__ edges, int* __restrict__ off,
                       int* __restrict__ endv, float* __restrict__ dinv,
                       const float2* __restrict__ x2, float2* __restrict__ xs2) {
    __shared__ int hist[1024];
    __shared__ int tmp[256];
    int b = blockIdx.x, tid = threadIdx.x;
    int cb0 = cbase[b], cb1 = cbase[b + 1];
    for (int k = 0; k < 4; ++k) hist[tid * 4 + k] = 0;
    __syncthreads();
    for (int j = cb0 + tid; j < cb1; j += 256)
        atomicAdd(&hist[stage[j] & BMASK], 1);
    __syncthreads();
    int c0 = hist[tid*4], c1 = hist[tid*4+1], c2 = hist[tid*4+2], c3 = hist[tid*4+3];
    int s = c0 + c1 + c2 + c3;
    int x = s; tmp[tid] = x; __syncthreads();
    for (int o = 1; o < 256; o <<= 1) {
        int y = (tid >= o) ? tmp[tid - o] : 0;
        __syncthreads();
        x += y; tmp[tid] = x;
        __syncthreads();
    }
    int run = x - s;                 // exclusive prefix of this thread's 4 counters
    int nbase = b << BSHIFT;
    int counts[4] = {c0, c1, c2, c3};
    for (int k = 0; k < 4; ++k) {
        int v = tid * 4 + k;
        hist[v] = run;               // local cursor start
        int node = nbase + v;
        if (node < N_NODES) {
            off[node]  = cb0 + run;
            endv[node] = cb0 + run + counts[k];
            float di = rsqrtf((float)counts[k] + 1.0f);   // +1 self loop
            dinv[node] = di;
            float2 xv = x2[node];
            xs2[node] = make_float2(di * xv.x, di * xv.y);
        }
        run += counts[k];
    }
    __syncthreads();
    for (int j = cb0 + tid; j < cb1; j += 256) {
        int p = stage[j];
        int pos = atomicAdd(&hist[p & BMASK], 1);
        edges[cb0 + pos] = p >> BSHIFT;     // src
    }
}

static __device__ __forceinline__ float rdlf(float v, int l) {
    return __uint_as_float(__builtin_amdgcn_readlane(__float_as_uint(v), (unsigned)l));
}
static __device__ __forceinline__ int rdli(int v, int l) {
    return __builtin_amdgcn_readlane(v, (unsigned)l);
}
// fp16 row fragment (4 channels) -> fp32 accumulate
static __device__ __forceinline__ void acc4h(float4& a, uint2 r) {
    __half2 h01 = *reinterpret_cast<const __half2*>(&r.x);
    __half2 h23 = *reinterpret_cast<const __half2*>(&r.y);
    float2 f01 = __half22float2(h01);
    float2 f23 = __half22float2(h23);
    a.x += f01.x; a.y += f01.y; a.z += f23.x; a.w += f23.y;
}

// ---------- layer 1: chunked gather of prescaled x + W1 + relu + fused W2,
//            store fp16 prescaled rows ----------
__global__ __launch_bounds__(256, 4)
void k_l1(const int* __restrict__ edges, const int* __restrict__ off,
          const int* __restrict__ endv, const float* __restrict__ dinv,
          const float2* __restrict__ xs2,
          const float* __restrict__ W1, const float* __restrict__ b1,
          const float* __restrict__ W2, __half* __restrict__ Yout) {
    int lane = threadIdx.x & 63;
    int wid = blockIdx.x * 4 + (threadIdx.x >> 6);
    int n0 = wid * CPW;
    if (n0 >= N_NODES) return;
    float w1a = W1[lane], w1b = W1[64 + lane], bb = b1[lane];
    float4 wc[16];
#pragma unroll
    for (int t = 0; t < 16; ++t) {
        wc[t].x = W2[(4 * t + 0) * 64 + lane];
        wc[t].y = W2[(4 * t + 1) * 64 + lane];
        wc[t].z = W2[(4 * t + 2) * 64 + lane];
        wc[t].w = W2[(4 * t + 3) * 64 + lane];
    }
#pragma unroll
    for (int t = 0; t < 16; ++t) {
        asm volatile("" : "+v"(wc[t].x), "+v"(wc[t].y), "+v"(wc[t].z), "+v"(wc[t].w));
    }
    // chunk metadata in lanes 0..15
    int mo = 0, me = 0; float md = 0.0f; float sxx = 0.0f, sxy = 0.0f;
    if (lane < CPW) {
        int nn = n0 + lane;
        mo = off[nn]; me = endv[nn]; md = dinv[nn];
        float2 sv = xs2[nn];
        sxx = sv.x; sxy = sv.y;
    }
    int j0 = rdli(mo, 0);
    int idx = j0 + lane; if (idx > N_EDGES - 1) idx = N_EDGES - 1;
    int ev = edges[idx];
    for (int i = 0; i < CPW; ++i) {
        int n = n0 + i;
        int j1 = rdli(me, i);
        float dn = rdlf(md, i);
        int deg = j1 - j0;
        int evn = 0; int j0n = 0;
        if (i < CPW - 1) {
            j0n = rdli(mo, i + 1);
            int idn = j0n + lane; if (idn > N_EDGES - 1) idn = N_EDGES - 1;
            evn = edges[idn];
        }
        float px = 0.0f, py = 0.0f;
        if (lane < deg) {                       // deg <= 64 (typ. ~16)
            float2 v = xs2[ev];
            px = v.x; py = v.y;
        }
        for (int jj = j0 + 64 + lane; jj < j1; jj += 64) {   // rare deg>64 tail
            float2 v = xs2[edges[jj]];
            px += v.x; py += v.y;
        }
#pragma unroll
        for (int o = 1; o < 64; o <<= 1) {
            px += __shfl_xor(px, o, 64);
            py += __shfl_xor(py, o, 64);
        }
        float gx = dn * (px + rdlf(sxx, i));
        float gy = dn * (py + rdlf(sxy, i));
        float h = gx * w1a + gy * w1b + bb;
        h = h > 0.0f ? h : 0.0f;
        float y0 = 0.0f, y1 = 0.0f, y2 = 0.0f, y3 = 0.0f;
#pragma unroll
        for (int t = 0; t < 16; ++t) {
            float4 w = wc[t];
            y0 = fmaf(rdlf(h, 4 * t + 0), w.x, y0);
            y1 = fmaf(rdlf(h, 4 * t + 1), w.y, y1);
            y2 = fmaf(rdlf(h, 4 * t + 2), w.z, y2);
            y3 = fmaf(rdlf(h, 4 * t + 3), w.w, y3);
        }
        Yout[n * 64 + lane] = __float2half(dn * ((y0 + y1) + (y2 + y3)));
        ev = evn; j0 = j0n;
    }
}

// ---------- layers 2/3: quad-row fp16 gather (4 rows per wave-load, fp32 accum)
//            + bias/relu (+ fused W_next transform via readlane) ----------
template<bool FINAL>
__global__ __launch_bounds__(256, 4)
void k_gl(const int* __restrict__ edges, const int* __restrict__ off,
          const int* __restrict__ endv, const float* __restrict__ dinv,
          const __half* __restrict__ Yin, const float* __restrict__ Wn,
          const float* __restrict__ bias, void* __restrict__ Yout) {
    const uint2* __restrict__ Yin2 = (const uint2*)Yin;   // 16 × 8B per 64-half row
    int lane = threadIdx.x & 63;
    int q = lane & 15, s = lane >> 4;          // sub-group: s = which row of a quad
    int wid = blockIdx.x * 4 + (threadIdx.x >> 6);
    int n0 = wid * CPW;
    if (n0 >= N_NODES) return;
    float bb = bias[lane];
    float4 wc[16];
    if (!FINAL) {
#pragma unroll
        for (int t = 0; t < 16; ++t) {
            wc[t].x = Wn[(4 * t + 0) * 64 + lane];
            wc[t].y = Wn[(4 * t + 1) * 64 + lane];
            wc[t].z = Wn[(4 * t + 2) * 64 + lane];
            wc[t].w = Wn[(4 * t + 3) * 64 + lane];
        }
#pragma unroll
        for (int t = 0; t < 16; ++t) {
            asm volatile("" : "+v"(wc[t].x), "+v"(wc[t].y), "+v"(wc[t].z), "+v"(wc[t].w));
        }
    }
    // chunk metadata in lanes 0..15
    int mo = 0, me = 0; float md = 0.0f;
    if (lane < CPW) {
        int nn = n0 + lane;
        mo = off[nn]; me = endv[nn]; md = dinv[nn];
    }
    int j0 = rdli(mo, 0);
    int idx = j0 + lane; if (idx > N_EDGES - 1) idx = N_EDGES - 1;
    int ev = edges[idx];                         // edge-index vector, node 0
    uint2 sraw = make_uint2(0u, 0u);
    if (s == 0) sraw = Yin2[(size_t)n0 * 16 + q];   // self row (prescaled fp16)
    for (int i = 0; i < CPW; ++i) {
        int n = n0 + i;
        int j1 = rdli(me, i);
        float dn = rdlf(md, i);
        int deg = j1 - j0;
        int evn = 0; int j0n = 0;
        uint2 srn = make_uint2(0u, 0u);
        if (i < CPW - 1) {                       // prefetch next node's vectors
            j0n = rdli(mo, i + 1);
            int idn = j0n + lane; if (idn > N_EDGES - 1) idn = N_EDGES - 1;
            evn = edges[idn];
            if (s == 0) srn = Yin2[(size_t)(n + 1) * 16 + q];
        }
        float4 acc = make_float4(0.f, 0.f, 0.f, 0.f);
        if (s == 0) acc4h(acc, sraw);
        int m = deg < 64 ? deg : 64;
        int t = 0;
        int fq4 = (m >> 2) & ~3;                 // full quads, multiple of 4
        for (; t < fq4; t += 4) {
            int i0 = __shfl(ev, 4 * t + s, 64);
            int i1 = __shfl(ev, 4 * t + 4 + s, 64);
            int i2 = __shfl(ev, 4 * t + 8 + s, 64);
            int i3 = __shfl(ev, 4 * t + 12 + s, 64);
            uint2 r0 = Yin2[(size_t)i0 * 16 + q];
            uint2 r1 = Yin2[(size_t)i1 * 16 + q];
            uint2 r2 = Yin2[(size_t)i2 * 16 + q];
            uint2 r3 = Yin2[(size_t)i3 * 16 + q];
            acc4h(acc, r0); acc4h(acc, r1); acc4h(acc, r2); acc4h(acc, r3);
        }
        for (; 4 * t < m; t += 2) {              // masked tail, 2-wide
            int e0 = 4 * t + s;
            int i0 = __shfl(ev, e0, 64);
            uint2 r0 = Yin2[(size_t)i0 * 16 + q];
            if (e0 < m) acc4h(acc, r0);
            if (4 * (t + 1) < m) {               // wave-uniform guard
                int e1 = 4 * t + 4 + s;
                int i1 = __shfl(ev, e1, 64);
                uint2 r1 = Yin2[(size_t)i1 * 16 + q];
                if (e1 < m) acc4h(acc, r1);
            }
        }
        for (int jj = 64; jj < deg; ++jj) {      // rare deg>64 tail (sub 0 only)
            int sidx = edges[j0 + jj];
            if (s == 0) {
                uint2 r = Yin2[(size_t)sidx * 16 + q];
                acc4h(acc, r);
            }
        }
        // combine the 4 sub-groups
        acc.x += __shfl_xor(acc.x, 16, 64); acc.x += __shfl_xor(acc.x, 32, 64);
        acc.y += __shfl_xor(acc.y, 16, 64); acc.y += __shfl_xor(acc.y, 32, 64);
        acc.z += __shfl_xor(acc.z, 16, 64); acc.z += __shfl_xor(acc.z, 32, 64);
        acc.w += __shfl_xor(acc.w, 16, 64); acc.w += __shfl_xor(acc.w, 32, 64);
        // redistribute: channel-per-lane layout
        int srcl = lane >> 2;
        float c0 = __shfl(acc.x, srcl, 64);
        float c1 = __shfl(acc.y, srcl, 64);
        float c2 = __shfl(acc.z, srcl, 64);
        float c3 = __shfl(acc.w, srcl, 64);
        float lo = (lane & 1) ? c1 : c0;
        float hi = (lane & 1) ? c3 : c2;
        float sumc = (lane & 2) ? hi : lo;
        float h = dn * sumc + bb;
        h = h > 0.0f ? h : 0.0f;
        if (FINAL) {
            ((float*)Yout)[n * 64 + lane] = h;
        } else {
            float y0 = 0.0f, y1 = 0.0f, y2 = 0.0f, y3 = 0.0f;
#pragma unroll
            for (int t2 = 0; t2 < 16; ++t2) {
                float4 w = wc[t2];
                y0 = fmaf(rdlf(h, 4 * t2 + 0), w.x, y0);
                y1 = fmaf(rdlf(h, 4 * t2 + 1), w.y, y1);
                y2 = fmaf(rdlf(h, 4 * t2 + 2), w.z, y2);
                y3 = fmaf(rdlf(h, 4 * t2 + 3), w.w, y3);
            }
            ((__half*)Yout)[n * 64 + lane] = __float2half(dn * ((y0 + y1) + (y2 + y3)));
        }
        ev = evn; sraw = srn; j0 = j0n;
    }
}

// ---------- segmented mean-pool accumulation (batch is sorted) ----------
#define PCHUNK 64
__global__ void k_pool(const float* __restrict__ A, const int* __restrict__ batch,
                       float* __restrict__ sums, float* __restrict__ cnts) {
    int c = threadIdx.x;
    int n0 = blockIdx.x * PCHUNK;
    int n1 = n0 + PCHUNK; if (n1 > N_NODES) n1 = N_NODES;
    int gcur = batch[n0];
    float acc = 0.0f;
    int cnt = 0;
    for (int n = n0; n < n1; ++n) {
        int g = batch[n];
        if (g != gcur) {
            atomicAdd(&sums[gcur * 64 + c], acc);
            if (c == 0) atomicAdd(&cnts[gcur], (float)cnt);
            acc = 0.0f; cnt = 0; gcur = g;
        }
        acc += A[n * 64 + c];
        ++cnt;
    }
    atomicAdd(&sums[gcur * 64 + c], acc);
    if (c == 0) atomicAdd(&cnts[gcur], (float)cnt);
}

// ---------- MLP head ----------
__global__ void k_head(const float* __restrict__ sums, const float* __restrict__ cnts,
                       const float* __restrict__ Wf1, const float* __restrict__ bf1,
                       const float* __restrict__ Wf2, const float* __restrict__ bf2,
                       float* __restrict__ out) {
    __shared__ float p[64];
    __shared__ float h[64];
    int g = blockIdx.x;
    int c = threadIdx.x;
    float cnt = cnts[g];
    cnt = cnt > 1.0f ? cnt : 1.0f;
    p[c] = sums[g * 64 + c] / cnt;
    __syncthreads();
    float s = bf1[c];
#pragma unroll
    for (int k = 0; k < 64; ++k) s += p[k] * Wf1[k * 64 + c];
    h[c] = s > 0.0f ? s : 0.0f;
    __syncthreads();
    if (c < N_CLASSES) {
        float o = bf2[c];
#pragma unroll
        for (int k = 0; k < 64; ++k) o += h[k] * Wf2[k * N_CLASSES + c];
        out[g * N_CLASSES + c] = o;
    }
}

extern "C" void kernel_launch(void* const* d_in, const int* in_sizes, int n_in,
                              void* d_out, int out_size, void* d_ws, size_t ws_size,
                              hipStream_t stream) {
    const float* x   = (const float*)d_in[0];
    const int*   ei  = (const int*)d_in[1];
    const int*   bat = (const int*)d_in[2];
    const float* W1  = (const float*)d_in[3];
    const float* b1  = (const float*)d_in[4];
    const float* W2  = (const float*)d_in[5];
    const float* b2  = (const float*)d_in[6];
    const float* W3  = (const float*)d_in[7];
    const float* b3  = (const float*)d_in[8];
    const float* Wf1 = (const float*)d_in[9];
    const float* bf1 = (const float*)d_in[10];
    const float* Wf2 = (const float*)d_in[11];
    const float* bf2 = (const float*)d_in[12];
    float* out = (float*)d_out;

    const int* src = ei;
    const int* dst = ei + N_EDGES;

    char* p = (char*)d_ws;
    float*  A    = (float*)p;   p += (size_t)N_NODES * 64 * 4;   // fp32 final acts
    __half* Ph   = (__half*)p;  p += (size_t)N_NODES * 64 * 2;   // fp16 prescaled (post-L1)
    __half* Qh   = (__half*)p;  p += (size_t)N_NODES * 64 * 2;   // fp16 prescaled (post-L2)
    int*   stage = (int*)p;     p += (size_t)N_EDGES * 4;
    int*   edges = (int*)p;     p += (size_t)N_EDGES * 4;
    int*   off   = (int*)p;     p += (size_t)N_NODES * 4;
    int*   endv  = (int*)p;     p += (size_t)N_NODES * 4;
    float* dinv  = (float*)p;   p += (size_t)N_NODES * 4;
    float* xs2   = (float*)p;   p += (size_t)N_NODES * 2 * 4;
    int*   chist = (int*)p;     p += (size_t)256 * 4;
    int*   cbase = (int*)p;     p += (size_t)256 * 4;
    int*   gcur  = (int*)p;     p += (size_t)256 * 4;
    float* sums  = (float*)p;   p += (size_t)N_GRAPHS * 64 * 4;
    float* cnts  = (float*)p;   p += (size_t)N_GRAPHS * 4;

    hipMemsetAsync(chist, 0, 256 * 4, stream);
    hipMemsetAsync(sums, 0, (size_t)(N_GRAPHS * 64 + N_GRAPHS) * 4, stream);

    const int BT = 256;
    int gChist = (N_EDGES + 256 * CH_EPT - 1) / (256 * CH_EPT);   // 782
    int gPart  = (N_EDGES + 256 * PT_EPT - 1) / (256 * PT_EPT);   // 391

    // ---- CSR build (binned, no global scatter over full buffer) ----
    k_chist<<<gChist, BT, 0, stream>>>(dst, chist);
    k_cscan<<<1, 256, 0, stream>>>(chist, cbase, gcur);
    k_part<<<gPart, BT, 0, stream>>>(src, dst, gcur, stage);
    k_sort<<<NBUCK, 256, 0, stream>>>(stage, cbase, edges, off, endv, dinv,
                                      (const float2*)x, (float2*)xs2);

    // ---- layer 1 (gather x, W1, relu, fused W2 transform + prescale, fp16 out) ----
    k_l1<<<GLAYER, BT, 0, stream>>>(edges, off, endv, dinv, (const float2*)xs2,
                                    W1, b1, W2, Ph);

    // ---- layer 2 (fp16 quad gather + b2/relu + fused W3 transform, fp16 out) ----
    k_gl<false><<<GLAYER, BT, 0, stream>>>(edges, off, endv, dinv, Ph, W3, b2, Qh);

    // ---- layer 3 (fp16 quad gather + b3/relu, fp32 final activations) ----
    k_gl<true><<<GLAYER, BT, 0, stream>>>(edges, off, endv, dinv, Qh, nullptr, b3, A);

    // ---- pool + head ----
    k_pool<<<(N_NODES + PCHUNK - 1) / PCHUNK, 64, 0, stream>>>(A, bat, sums, cnts);
    k_head<<<N_GRAPHS, 64, 0, stream>>>(sums, cnts, Wf1, bf1, Wf2, bf2, out);
}

// Round 12
// 472.432 us; speedup vs baseline: 1.2463x; 1.0641x over previous
//
#include <hip/hip_runtime.h>
#include <hip/hip_fp16.h>

#define N_NODES  200000
#define N_EDGES  3200000
#define HIDDEN   64
#define N_GRAPHS 4096
#define N_CLASSES 7
#define NBUCK    196          // ceil(N_NODES / 1024)
#define BSHIFT   10
#define BMASK    1023
#define CPW      16           // nodes (chunk) per wave
#define NCHUNK   (N_NODES / CPW)          // 12500
#define GLAYER   (NCHUNK / 4)             // 3125 blocks of 4 waves

// ---------- coarse histogram (196 buckets) ----------
#define CH_EPT 16
__global__ void k_chist(const int* __restrict__ dst, int* __restrict__ chist) {
    __shared__ int h[NBUCK];
    for (int i = threadIdx.x; i < NBUCK; i += 256) h[i] = 0;
    __syncthreads();
    int base = blockIdx.x * 256 * CH_EPT + threadIdx.x;
    for (int k = 0; k < CH_EPT; ++k) {
        int e = base + k * 256;
        if (e < N_EDGES) atomicAdd(&h[dst[e] >> BSHIFT], 1);
    }
    __syncthreads();
    for (int i = threadIdx.x; i < NBUCK; i += 256) atomicAdd(&chist[i], h[i]);
}

// ---------- scan of 196 bucket counts ----------
__global__ void k_cscan(const int* __restrict__ chist, int* __restrict__ cbase,
                        int* __restrict__ gcur) {
    __shared__ int tmp[256];
    int tid = threadIdx.x;
    int v = (tid < NBUCK) ? chist[tid] : 0;
    int x = v; tmp[tid] = x; __syncthreads();
    for (int o = 1; o < 256; o <<= 1) {
        int y = (tid >= o) ? tmp[tid - o] : 0;
        __syncthreads();
        x += y; tmp[tid] = x;
        __syncthreads();
    }
    if (tid < NBUCK) { cbase[tid] = x - v; gcur[tid] = x - v; }
    if (tid == 0) cbase[NBUCK] = N_EDGES;
}

// ---------- coarse partition: stage[pos] = (src<<10)|(dst&1023) ----------
#define PT_EPT 32
__global__ void k_part(const int* __restrict__ src, const int* __restrict__ dst,
                       int* __restrict__ gcur, int* __restrict__ stage) {
    __shared__ int lh[NBUCK];
    __shared__ int lbase[NBUCK];
    __shared__ int lcur[NBUCK];
    for (int i = threadIdx.x; i < NBUCK; i += 256) { lh[i] = 0; lcur[i] = 0; }
    __syncthreads();
    int base = blockIdx.x * 256 * PT_EPT + threadIdx.x;
    for (int k = 0; k < PT_EPT; ++k) {
        int e = base + k * 256;
        if (e < N_EDGES) atomicAdd(&lh[dst[e] >> BSHIFT], 1);
    }
    __syncthreads();
    for (int i = threadIdx.x; i < NBUCK; i += 256)
        if (lh[i] > 0) lbase[i] = atomicAdd(&gcur[i], lh[i]);
    __syncthreads();
    for (int k = 0; k < PT_EPT; ++k) {
        int e = base + k * 256;
        if (e < N_EDGES) {
            int d = dst[e], b = d >> BSHIFT;
            int lp = atomicAdd(&lcur[b], 1);
            stage[lbase[b] + lp] = (src[e] << BSHIFT) | (d & BMASK);
        }
    }
}

// ---------- per-bucket exact sort + CSR metadata; also prescale x by dinv ----------
__global__ void k_sort(const int* __restrict__ stage, const int* __restrict__ cbase,
                       int* __restrict__ edges, int* __restrict__ off,
                       int* __restrict__ endv, float* __restrict__ dinv,
                       const float2* __restrict__ x2, float2* __restrict__ xs2) {
    __shared__ int hist[1024];
    __shared__ int tmp[256];
    int b = blockIdx.x, tid = threadIdx.x;
    int cb0 = cbase[b], cb1 = cbase[b + 1];
    for (int k = 0; k < 4; ++k) hist[tid * 4 + k] = 0;
    __syncthreads();
    for (int j = cb0 + tid; j < cb1; j += 256)
        atomicAdd(&hist[stage[j] & BMASK], 1);
    __syncthreads();
    int c0 = hist[tid*4], c1 = hist[tid*4+1], c2 = hist[tid*4+2], c3 = hist[tid*4+3];
    int s = c0 + c1 + c2 + c3;
    int x = s; tmp[tid] = x; __syncthreads();
    for (int o = 1; o < 256; o <<= 1) {
        int y = (tid >= o) ? tmp[tid - o] : 0;
        __syncthreads();
        x += y; tmp[tid] = x;
        __syncthreads();
    }
    int run = x - s;                 // exclusive prefix of this thread's 4 counters
    int nbase = b << BSHIFT;
    int counts[4] = {c0, c1, c2, c3};
    for (int k = 0; k < 4; ++k) {
        int v = tid * 4 + k;
        hist[v] = run;               // local cursor start
        int node = nbase + v;
        if (node < N_NODES) {
            off[node]  = cb0 + run;
            endv[node] = cb0 + run + counts[k];
            float di = rsqrtf((float)counts[k] + 1.0f);   // +1 self loop
            dinv[node] = di;
            float2 xv = x2[node];
            xs2[node] = make_float2(di * xv.x, di * xv.y);
        }
        run += counts[k];
    }
    __syncthreads();
    for (int j = cb0 + tid; j < cb1; j += 256) {
        int p = stage[j];
        int pos = atomicAdd(&hist[p & BMASK], 1);
        edges[cb0 + pos] = p >> BSHIFT;     // src
    }
}

static __device__ __forceinline__ float rdlf(float v, int l) {
    return __uint_as_float(__builtin_amdgcn_readlane(__float_as_uint(v), (unsigned)l));
}
static __device__ __forceinline__ int rdli(int v, int l) {
    return __builtin_amdgcn_readlane(v, (unsigned)l);
}
// fp16 row fragment (4 channels) -> fp32 accumulate
static __device__ __forceinline__ void acc4h(float4& a, uint2 r) {
    __half2 h01 = *reinterpret_cast<const __half2*>(&r.x);
    __half2 h23 = *reinterpret_cast<const __half2*>(&r.y);
    float2 f01 = __half22float2(h01);
    float2 f23 = __half22float2(h23);
    a.x += f01.x; a.y += f01.y; a.z += f23.x; a.w += f23.y;
}

// ---------- layer 1: chunked gather of prescaled x + W1 + relu + fused W2,
//            store fp16 prescaled rows ----------
__global__ __launch_bounds__(256, 4)
void k_l1(const int* __restrict__ edges, const int* __restrict__ off,
          const int* __restrict__ endv, const float* __restrict__ dinv,
          const float2* __restrict__ xs2,
          const float* __restrict__ W1, const float* __restrict__ b1,
          const float* __restrict__ W2, __half* __restrict__ Yout) {
    int lane = threadIdx.x & 63;
    int wid = blockIdx.x * 4 + (threadIdx.x >> 6);
    int n0 = wid * CPW;
    if (n0 >= N_NODES) return;
    float w1a = W1[lane], w1b = W1[64 + lane], bb = b1[lane];
    float4 wc[16];
#pragma unroll
    for (int t = 0; t < 16; ++t) {
        wc[t].x = W2[(4 * t + 0) * 64 + lane];
        wc[t].y = W2[(4 * t + 1) * 64 + lane];
        wc[t].z = W2[(4 * t + 2) * 64 + lane];
        wc[t].w = W2[(4 * t + 3) * 64 + lane];
    }
#pragma unroll
    for (int t = 0; t < 16; ++t) {
        asm volatile("" : "+v"(wc[t].x), "+v"(wc[t].y), "+v"(wc[t].z), "+v"(wc[t].w));
    }
    // chunk metadata in lanes 0..15
    int mo = 0, me = 0; float md = 0.0f; float sxx = 0.0f, sxy = 0.0f;
    if (lane < CPW) {
        int nn = n0 + lane;
        mo = off[nn]; me = endv[nn]; md = dinv[nn];
        float2 sv = xs2[nn];
        sxx = sv.x; sxy = sv.y;
    }
    int j0 = rdli(mo, 0);
    int idx = j0 + lane; if (idx > N_EDGES - 1) idx = N_EDGES - 1;
    int ev = edges[idx];
    for (int i = 0; i < CPW; ++i) {
        int n = n0 + i;
        int j1 = rdli(me, i);
        float dn = rdlf(md, i);
        int deg = j1 - j0;
        int evn = 0; int j0n = 0;
        if (i < CPW - 1) {
            j0n = rdli(mo, i + 1);
            int idn = j0n + lane; if (idn > N_EDGES - 1) idn = N_EDGES - 1;
            evn = edges[idn];
        }
        float px = 0.0f, py = 0.0f;
        if (lane < deg) {                       // deg <= 64 (typ. ~16)
            float2 v = xs2[ev];
            px = v.x; py = v.y;
        }
        for (int jj = j0 + 64 + lane; jj < j1; jj += 64) {   // rare deg>64 tail
            float2 v = xs2[edges[jj]];
            px += v.x; py += v.y;
        }
#pragma unroll
        for (int o = 1; o < 64; o <<= 1) {
            px += __shfl_xor(px, o, 64);
            py += __shfl_xor(py, o, 64);
        }
        float gx = dn * (px + rdlf(sxx, i));
        float gy = dn * (py + rdlf(sxy, i));
        float h = gx * w1a + gy * w1b + bb;
        h = h > 0.0f ? h : 0.0f;
        float y0 = 0.0f, y1 = 0.0f, y2 = 0.0f, y3 = 0.0f;
#pragma unroll
        for (int t = 0; t < 16; ++t) {
            float4 w = wc[t];
            y0 = fmaf(rdlf(h, 4 * t + 0), w.x, y0);
            y1 = fmaf(rdlf(h, 4 * t + 1), w.y, y1);
            y2 = fmaf(rdlf(h, 4 * t + 2), w.z, y2);
            y3 = fmaf(rdlf(h, 4 * t + 3), w.w, y3);
        }
        Yout[n * 64 + lane] = __float2half(dn * ((y0 + y1) + (y2 + y3)));
        ev = evn; j0 = j0n;
    }
}

// ---------- layers 2/3: software-pipelined quad-row fp16 gather:
//            node i+1's first-16-edge row loads issue BEFORE node i's
//            reduce+transform (latency hides under ~300 VALU cycles) ----------
template<bool FINAL>
__global__ __launch_bounds__(256, 4)
void k_gl(const int* __restrict__ edges, const int* __restrict__ off,
          const int* __restrict__ endv, const float* __restrict__ dinv,
          const __half* __restrict__ Yin, const float* __restrict__ Wn,
          const float* __restrict__ bias, void* __restrict__ Yout) {
    const uint2* __restrict__ Yin2 = (const uint2*)Yin;   // 16 × 8B per 64-half row
    int lane = threadIdx.x & 63;
    int q = lane & 15, s = lane >> 4;          // sub-group: s = which row of a quad
    int wid = blockIdx.x * 4 + (threadIdx.x >> 6);
    int n0 = wid * CPW;
    if (n0 >= N_NODES) return;
    float bb = bias[lane];
    float4 wc[16];
    if (!FINAL) {
#pragma unroll
        for (int t = 0; t < 16; ++t) {
            wc[t].x = Wn[(4 * t + 0) * 64 + lane];
            wc[t].y = Wn[(4 * t + 1) * 64 + lane];
            wc[t].z = Wn[(4 * t + 2) * 64 + lane];
            wc[t].w = Wn[(4 * t + 3) * 64 + lane];
        }
#pragma unroll
        for (int t = 0; t < 16; ++t) {
            asm volatile("" : "+v"(wc[t].x), "+v"(wc[t].y), "+v"(wc[t].z), "+v"(wc[t].w));
        }
    }
    // chunk metadata in lanes 0..15
    int mo = 0, me = 0; float md = 0.0f;
    if (lane < CPW) {
        int nn = n0 + lane;
        mo = off[nn]; me = endv[nn]; md = dinv[nn];
    }
    int j0 = rdli(mo, 0);
    int j1 = rdli(me, 0);
    int m0 = j1 - j0; if (m0 > 64) m0 = 64;
    int idx = j0 + lane; if (idx > N_EDGES - 1) idx = N_EDGES - 1;
    int ev = edges[idx];                         // edge-index vector, node 0
    uint2 sraw = make_uint2(0u, 0u);
    if (s == 0) sraw = Yin2[(size_t)n0 * 16 + q];   // self row (prescaled fp16)
    // prologue: prefetch node 0's first-16-edge rows (group guards wave-uniform)
    uint2 r0 = make_uint2(0u, 0u), r1 = r0, r2 = r0, r3 = r0;
    {
        int i0 = __shfl(ev, 0 + s, 64);
        int i1 = __shfl(ev, 4 + s, 64);
        int i2 = __shfl(ev, 8 + s, 64);
        int i3 = __shfl(ev, 12 + s, 64);
        if (m0 > 0)  r0 = Yin2[(size_t)i0 * 16 + q];
        if (m0 > 4)  r1 = Yin2[(size_t)i1 * 16 + q];
        if (m0 > 8)  r2 = Yin2[(size_t)i2 * 16 + q];
        if (m0 > 12) r3 = Yin2[(size_t)i3 * 16 + q];
    }
    for (int i = 0; i < CPW; ++i) {
        int n = n0 + i;
        float dn = rdlf(md, i);
        int deg = rdli(me, i) - j0;
        int m = m0;
        // next node's metadata + edge vector + self row (issue early)
        int evn = 0; int j0n = 0; int mn = 0;
        uint2 srn = make_uint2(0u, 0u);
        if (i < CPW - 1) {
            j0n = rdli(mo, i + 1);
            int j1n = rdli(me, i + 1);
            mn = j1n - j0n; if (mn > 64) mn = 64;
            int idn = j0n + lane; if (idn > N_EDGES - 1) idn = N_EDGES - 1;
            evn = edges[idn];
            if (s == 0) srn = Yin2[(size_t)(n + 1) * 16 + q];
        }
        // ---- accumulate prefetched first-16 rows (per-lane slot mask) ----
        float4 acc = make_float4(0.f, 0.f, 0.f, 0.f);
        if (s == 0) acc4h(acc, sraw);
        if (0 + s < m)  acc4h(acc, r0);
        if (4 + s < m)  acc4h(acc, r1);
        if (8 + s < m)  acc4h(acc, r2);
        if (12 + s < m) acc4h(acc, r3);
        // ---- remainder 16..m in-line (uniform group bound, per-lane mask) ----
        for (int t = 4; 4 * t < m; ++t) {
            int sl = 4 * t + s;
            int ii = __shfl(ev, sl, 64);
            uint2 rr = Yin2[(size_t)ii * 16 + q];
            if (sl < m) acc4h(acc, rr);
        }
        // ---- rare deg>64 tail (sub 0 only) ----
        for (int jj = 64; jj < deg; ++jj) {
            int sidx = edges[j0 + jj];
            if (s == 0) {
                uint2 rr = Yin2[(size_t)sidx * 16 + q];
                acc4h(acc, rr);
            }
        }
        // ---- PREFETCH next node's rows: results not used until next iter,
        //      so the vmcnt wait lands after the transform below ----
        if (i < CPW - 1) {
            int i0 = __shfl(evn, 0 + s, 64);
            int i1 = __shfl(evn, 4 + s, 64);
            int i2 = __shfl(evn, 8 + s, 64);
            int i3 = __shfl(evn, 12 + s, 64);
            r0 = make_uint2(0u, 0u); r1 = r0; r2 = r0; r3 = r0;
            if (mn > 0)  r0 = Yin2[(size_t)i0 * 16 + q];
            if (mn > 4)  r1 = Yin2[(size_t)i1 * 16 + q];
            if (mn > 8)  r2 = Yin2[(size_t)i2 * 16 + q];
            if (mn > 12) r3 = Yin2[(size_t)i3 * 16 + q];
        }
        // ---- combine the 4 sub-groups (long VALU stretch covers prefetch) ----
        acc.x += __shfl_xor(acc.x, 16, 64); acc.x += __shfl_xor(acc.x, 32, 64);
        acc.y += __shfl_xor(acc.y, 16, 64); acc.y += __shfl_xor(acc.y, 32, 64);
        acc.z += __shfl_xor(acc.z, 16, 64); acc.z += __shfl_xor(acc.z, 32, 64);
        acc.w += __shfl_xor(acc.w, 16, 64); acc.w += __shfl_xor(acc.w, 32, 64);
        // redistribute: channel-per-lane layout
        int srcl = lane >> 2;
        float c0 = __shfl(acc.x, srcl, 64);
        float c1 = __shfl(acc.y, srcl, 64);
        float c2 = __shfl(acc.z, srcl, 64);
        float c3 = __shfl(acc.w, srcl, 64);
        float lo = (lane & 1) ? c1 : c0;
        float hi = (lane & 1) ? c3 : c2;
        float sumc = (lane & 2) ? hi : lo;
        float h = dn * sumc + bb;
        h = h > 0.0f ? h : 0.0f;
        if (FINAL) {
            ((float*)Yout)[n * 64 + lane] = h;
        } else {
            float y0 = 0.0f, y1 = 0.0f, y2 = 0.0f, y3 = 0.0f;
#pragma unroll
            for (int t2 = 0; t2 < 16; ++t2) {
                float4 w = wc[t2];
                y0 = fmaf(rdlf(h, 4 * t2 + 0), w.x, y0);
                y1 = fmaf(rdlf(h, 4 * t2 + 1), w.y, y1);
                y2 = fmaf(rdlf(h, 4 * t2 + 2), w.z, y2);
                y3 = fmaf(rdlf(h, 4 * t2 + 3), w.w, y3);
            }
            ((__half*)Yout)[n * 64 + lane] = __float2half(dn * ((y0 + y1) + (y2 + y3)));
        }
        ev = evn; sraw = srn; j0 = j0n; m0 = mn;
    }
}

// ---------- segmented mean-pool accumulation (batch is sorted) ----------
#define PCHUNK 64
__global__ void k_pool(const float* __restrict__ A, const int* __restrict__ batch,
                       float* __restrict__ sums, float* __restrict__ cnts) {
    int c = threadIdx.x;
    int n0 = blockIdx.x * PCHUNK;
    int n1 = n0 + PCHUNK; if (n1 > N_NODES) n1 = N_NODES;
    int gcur = batch[n0];
    float acc = 0.0f;
    int cnt = 0;
    for (int n = n0; n < n1; ++n) {
        int g = batch[n];
        if (g != gcur) {
            atomicAdd(&sums[gcur * 64 + c], acc);
            if (c == 0) atomicAdd(&cnts[gcur], (float)cnt);
            acc = 0.0f; cnt = 0; gcur = g;
        }
        acc += A[n * 64 + c];
        ++cnt;
    }
    atomicAdd(&sums[gcur * 64 + c], acc);
    if (c == 0) atomicAdd(&cnts[gcur], (float)cnt);
}

// ---------- MLP head ----------
__global__ void k_head(const float* __restrict__ sums, const float* __restrict__ cnts,
                       const float* __restrict__ Wf1, const float* __restrict__ bf1,
                       const float* __restrict__ Wf2, const float* __restrict__ bf2,
                       float* __restrict__ out) {
    __shared__ float p[64];
    __shared__ float h[64];
    int g = blockIdx.x;
    int c = threadIdx.x;
    float cnt = cnts[g];
    cnt = cnt > 1.0f ? cnt : 1.0f;
    p[c] = sums[g * 64 + c] / cnt;
    __syncthreads();
    float s = bf1[c];
#pragma unroll
    for (int k = 0; k < 64; ++k) s += p[k] * Wf1[k * 64 + c];
    h[c] = s > 0.0f ? s : 0.0f;
    __syncthreads();
    if (c < N_CLASSES) {
        float o = bf2[c];
#pragma unroll
        for (int k = 0; k < 64; ++k) o += h[k] * Wf2[k * N_CLASSES + c];
        out[g * N_CLASSES + c] = o;
    }
}

extern "C" void kernel_launch(void* const* d_in, const int* in_sizes, int n_in,
                              void* d_out, int out_size, void* d_ws, size_t ws_size,
                              hipStream_t stream) {
    const float* x   = (const float*)d_in[0];
    const int*   ei  = (const int*)d_in[1];
    const int*   bat = (const int*)d_in[2];
    const float* W1  = (const float*)d_in[3];
    const float* b1  = (const float*)d_in[4];
    const float* W2  = (const float*)d_in[5];
    const float* b2  = (const float*)d_in[6];
    const float* W3  = (const float*)d_in[7];
    const float* b3  = (const float*)d_in[8];
    const float* Wf1 = (const float*)d_in[9];
    const float* bf1 = (const float*)d_in[10];
    const float* Wf2 = (const float*)d_in[11];
    const float* bf2 = (const float*)d_in[12];
    float* out = (float*)d_out;

    const int* src = ei;
    const int* dst = ei + N_EDGES;

    char* p = (char*)d_ws;
    float*  A    = (float*)p;   p += (size_t)N_NODES * 64 * 4;   // fp32 final acts
    __half* Ph   = (__half*)p;  p += (size_t)N_NODES * 64 * 2;   // fp16 prescaled (post-L1)
    __half* Qh   = (__half*)p;  p += (size_t)N_NODES * 64 * 2;   // fp16 prescaled (post-L2)
    int*   stage = (int*)p;     p += (size_t)N_EDGES * 4;
    int*   edges = (int*)p;     p += (size_t)N_EDGES * 4;
    int*   off   = (int*)p;     p += (size_t)N_NODES * 4;
    int*   endv  = (int*)p;     p += (size_t)N_NODES * 4;
    float* dinv  = (float*)p;   p += (size_t)N_NODES * 4;
    float* xs2   = (float*)p;   p += (size_t)N_NODES * 2 * 4;
    int*   chist = (int*)p;     p += (size_t)256 * 4;
    int*   cbase = (int*)p;     p += (size_t)256 * 4;
    int*   gcur  = (int*)p;     p += (size_t)256 * 4;
    float* sums  = (float*)p;   p += (size_t)N_GRAPHS * 64 * 4;
    float* cnts  = (float*)p;   p += (size_t)N_GRAPHS * 4;

    hipMemsetAsync(chist, 0, 256 * 4, stream);
    hipMemsetAsync(sums, 0, (size_t)(N_GRAPHS * 64 + N_GRAPHS) * 4, stream);

    const int BT = 256;
    int gChist = (N_EDGES + 256 * CH_EPT - 1) / (256 * CH_EPT);   // 782
    int gPart  = (N_EDGES + 256 * PT_EPT - 1) / (256 * PT_EPT);   // 391

    // ---- CSR build (binned, no global scatter over full buffer) ----
    k_chist<<<gChist, BT, 0, stream>>>(dst, chist);
    k_cscan<<<1, 256, 0, stream>>>(chist, cbase, gcur);
    k_part<<<gPart, BT, 0, stream>>>(src, dst, gcur, stage);
    k_sort<<<NBUCK, 256, 0, stream>>>(stage, cbase, edges, off, endv, dinv,
                                      (const float2*)x, (float2*)xs2);

    // ---- layer 1 (gather x, W1, relu, fused W2 transform + prescale, fp16 out) ----
    k_l1<<<GLAYER, BT, 0, stream>>>(edges, off, endv, dinv, (const float2*)xs2,
                                    W1, b1, W2, Ph);

    // ---- layer 2 (pipelined fp16 quad gather + b2/relu + fused W3, fp16 out) ----
    k_gl<false><<<GLAYER, BT, 0, stream>>>(edges, off, endv, dinv, Ph, W3, b2, Qh);

    // ---- layer 3 (pipelined fp16 quad gather + b3/relu, fp32 final acts) ----
    k_gl<true><<<GLAYER, BT, 0, stream>>>(edges, off, endv, dinv, Qh, nullptr, b3, A);

    // ---- pool + head ----
    k_pool<<<(N_NODES + PCHUNK - 1) / PCHUNK, 64, 0, stream>>>(A, bat, sums, cnts);
    k_head<<<N_GRAPHS, 64, 0, stream>>>(sums, cnts, Wf1, bf1, Wf2, bf2, out);
}

// Round 13
// 467.015 us; speedup vs baseline: 1.2607x; 1.0116x over previous
//
#include <hip/hip_runtime.h>
#include <hip/hip_fp16.h>

#define N_NODES  200000
#define N_EDGES  3200000
#define HIDDEN   64
#define N_GRAPHS 4096
#define N_CLASSES 7
#define NBUCK    196          // ceil(N_NODES / 1024)
#define BSHIFT   10
#define BMASK    1023
#define CPW      16           // nodes (chunk) per wave
#define NCHUNK   (N_NODES / CPW)          // 12500
#define GLAYER   (NCHUNK / 4)             // 3125 blocks of 4 waves

// ---------- coarse histogram (196 buckets) ----------
#define CH_EPT 16
__global__ void k_chist(const int* __restrict__ dst, int* __restrict__ chist) {
    __shared__ int h[NBUCK];
    for (int i = threadIdx.x; i < NBUCK; i += 256) h[i] = 0;
    __syncthreads();
    int base = blockIdx.x * 256 * CH_EPT + threadIdx.x;
    for (int k = 0; k < CH_EPT; ++k) {
        int e = base + k * 256;
        if (e < N_EDGES) atomicAdd(&h[dst[e] >> BSHIFT], 1);
    }
    __syncthreads();
    for (int i = threadIdx.x; i < NBUCK; i += 256) atomicAdd(&chist[i], h[i]);
}

// ---------- scan of 196 bucket counts ----------
__global__ void k_cscan(const int* __restrict__ chist, int* __restrict__ cbase,
                        int* __restrict__ gcur) {
    __shared__ int tmp[256];
    int tid = threadIdx.x;
    int v = (tid < NBUCK) ? chist[tid] : 0;
    int x = v; tmp[tid] = x; __syncthreads();
    for (int o = 1; o < 256; o <<= 1) {
        int y = (tid >= o) ? tmp[tid - o] : 0;
        __syncthreads();
        x += y; tmp[tid] = x;
        __syncthreads();
    }
    if (tid < NBUCK) { cbase[tid] = x - v; gcur[tid] = x - v; }
    if (tid == 0) cbase[NBUCK] = N_EDGES;
}

// ---------- coarse partition: stage[pos] = (src<<10)|(dst&1023) ----------
#define PT_EPT 32
__global__ void k_part(const int* __restrict__ src, const int* __restrict__ dst,
                       int* __restrict__ gcur, int* __restrict__ stage) {
    __shared__ int lh[NBUCK];
    __shared__ int lbase[NBUCK];
    __shared__ int lcur[NBUCK];
    for (int i = threadIdx.x; i < NBUCK; i += 256) { lh[i] = 0; lcur[i] = 0; }
    __syncthreads();
    int base = blockIdx.x * 256 * PT_EPT + threadIdx.x;
    for (int k = 0; k < PT_EPT; ++k) {
        int e = base + k * 256;
        if (e < N_EDGES) atomicAdd(&lh[dst[e] >> BSHIFT], 1);
    }
    __syncthreads();
    for (int i = threadIdx.x; i < NBUCK; i += 256)
        if (lh[i] > 0) lbase[i] = atomicAdd(&gcur[i], lh[i]);
    __syncthreads();
    for (int k = 0; k < PT_EPT; ++k) {
        int e = base + k * 256;
        if (e < N_EDGES) {
            int d = dst[e], b = d >> BSHIFT;
            int lp = atomicAdd(&lcur[b], 1);
            stage[lbase[b] + lp] = (src[e] << BSHIFT) | (d & BMASK);
        }
    }
}

// ---------- per-bucket exact sort + CSR metadata; also prescale x by dinv ----------
__global__ void k_sort(const int* __restrict__ stage, const int* __restrict__ cbase,
                       int* __restrict__ edges, int* __restrict__ off,
                       int* __restrict__ endv, float* __restrict__ dinv,
                       const float2* __restrict__ x2, float2* __restrict__ xs2) {
    __shared__ int hist[1024];
    __shared__ int tmp[256];
    int b = blockIdx.x, tid = threadIdx.x;
    int cb0 = cbase[b], cb1 = cbase[b + 1];
    for (int k = 0; k < 4; ++k) hist[tid * 4 + k] = 0;
    __syncthreads();
    for (int j = cb0 + tid; j < cb1; j += 256)
        atomicAdd(&hist[stage[j] & BMASK], 1);
    __syncthreads();
    int c0 = hist[tid*4], c1 = hist[tid*4+1], c2 = hist[tid*4+2], c3 = hist[tid*4+3];
    int s = c0 + c1 + c2 + c3;
    int x = s; tmp[tid] = x; __syncthreads();
    for (int o = 1; o < 256; o <<= 1) {
        int y = (tid >= o) ? tmp[tid - o] : 0;
        __syncthreads();
        x += y; tmp[tid] = x;
        __syncthreads();
    }
    int run = x - s;                 // exclusive prefix of this thread's 4 counters
    int nbase = b << BSHIFT;
    int counts[4] = {c0, c1, c2, c3};
    for (int k = 0; k < 4; ++k) {
        int v = tid * 4 + k;
        hist[v] = run;               // local cursor start
        int node = nbase + v;
        if (node < N_NODES) {
            off[node]  = cb0 + run;
            endv[node] = cb0 + run + counts[k];
            float di = rsqrtf((float)counts[k] + 1.0f);   // +1 self loop
            dinv[node] = di;
            float2 xv = x2[node];
            xs2[node] = make_float2(di * xv.x, di * xv.y);
        }
        run += counts[k];
    }
    __syncthreads();
    for (int j = cb0 + tid; j < cb1; j += 256) {
        int p = stage[j];
        int pos = atomicAdd(&hist[p & BMASK], 1);
        edges[cb0 + pos] = p >> BSHIFT;     // src
    }
}

static __device__ __forceinline__ float rdlf(float v, int l) {
    return __uint_as_float(__builtin_amdgcn_readlane(__float_as_uint(v), (unsigned)l));
}
static __device__ __forceinline__ int rdli(int v, int l) {
    return __builtin_amdgcn_readlane(v, (unsigned)l);
}
// fp16 row fragment (4 channels) -> fp32 accumulate
static __device__ __forceinline__ void acc4h(float4& a, uint2 r) {
    __half2 h01 = *reinterpret_cast<const __half2*>(&r.x);
    __half2 h23 = *reinterpret_cast<const __half2*>(&r.y);
    float2 f01 = __half22float2(h01);
    float2 f23 = __half22float2(h23);
    a.x += f01.x; a.y += f01.y; a.z += f23.x; a.w += f23.y;
}

// ---------- layer 1: chunked gather of prescaled x + W1 + relu + fused W2,
//            store fp16 prescaled rows ----------
__global__ __launch_bounds__(256, 4)
void k_l1(const int* __restrict__ edges, const int* __restrict__ off,
          const int* __restrict__ endv, const float* __restrict__ dinv,
          const float2* __restrict__ xs2,
          const float* __restrict__ W1, const float* __restrict__ b1,
          const float* __restrict__ W2, __half* __restrict__ Yout) {
    int lane = threadIdx.x & 63;
    int wid = blockIdx.x * 4 + (threadIdx.x >> 6);
    int n0 = wid * CPW;
    if (n0 >= N_NODES) return;
    float w1a = W1[lane], w1b = W1[64 + lane], bb = b1[lane];
    float4 wc[16];
#pragma unroll
    for (int t = 0; t < 16; ++t) {
        wc[t].x = W2[(4 * t + 0) * 64 + lane];
        wc[t].y = W2[(4 * t + 1) * 64 + lane];
        wc[t].z = W2[(4 * t + 2) * 64 + lane];
        wc[t].w = W2[(4 * t + 3) * 64 + lane];
    }
#pragma unroll
    for (int t = 0; t < 16; ++t) {
        asm volatile("" : "+v"(wc[t].x), "+v"(wc[t].y), "+v"(wc[t].z), "+v"(wc[t].w));
    }
    // chunk metadata in lanes 0..15
    int mo = 0, me = 0; float md = 0.0f; float sxx = 0.0f, sxy = 0.0f;
    if (lane < CPW) {
        int nn = n0 + lane;
        mo = off[nn]; me = endv[nn]; md = dinv[nn];
        float2 sv = xs2[nn];
        sxx = sv.x; sxy = sv.y;
    }
    int j0 = rdli(mo, 0);
    int idx = j0 + lane; if (idx > N_EDGES - 1) idx = N_EDGES - 1;
    int ev = edges[idx];
    for (int i = 0; i < CPW; ++i) {
        int n = n0 + i;
        int j1 = rdli(me, i);
        float dn = rdlf(md, i);
        int deg = j1 - j0;
        int evn = 0; int j0n = 0;
        if (i < CPW - 1) {
            j0n = rdli(mo, i + 1);
            int idn = j0n + lane; if (idn > N_EDGES - 1) idn = N_EDGES - 1;
            evn = edges[idn];
        }
        float px = 0.0f, py = 0.0f;
        if (lane < deg) {                       // deg <= 64 (typ. ~16)
            float2 v = xs2[ev];
            px = v.x; py = v.y;
        }
        for (int jj = j0 + 64 + lane; jj < j1; jj += 64) {   // rare deg>64 tail
            float2 v = xs2[edges[jj]];
            px += v.x; py += v.y;
        }
#pragma unroll
        for (int o = 1; o < 64; o <<= 1) {
            px += __shfl_xor(px, o, 64);
            py += __shfl_xor(py, o, 64);
        }
        float gx = dn * (px + rdlf(sxx, i));
        float gy = dn * (py + rdlf(sxy, i));
        float h = gx * w1a + gy * w1b + bb;
        h = h > 0.0f ? h : 0.0f;
        float y0 = 0.0f, y1 = 0.0f, y2 = 0.0f, y3 = 0.0f;
#pragma unroll
        for (int t = 0; t < 16; ++t) {
            float4 w = wc[t];
            y0 = fmaf(rdlf(h, 4 * t + 0), w.x, y0);
            y1 = fmaf(rdlf(h, 4 * t + 1), w.y, y1);
            y2 = fmaf(rdlf(h, 4 * t + 2), w.z, y2);
            y3 = fmaf(rdlf(h, 4 * t + 3), w.w, y3);
        }
        Yout[n * 64 + lane] = __float2half(dn * ((y0 + y1) + (y2 + y3)));
        ev = evn; j0 = j0n;
    }
}

// ---------- layers 2/3: software-pipelined quad-row fp16 gather, 32-slot
//            prefetch (group-guarded, no waste): node i+1's first-32-edge
//            rows issue BEFORE node i's reduce+transform ----------
template<bool FINAL>
__global__ __launch_bounds__(256, 4)
void k_gl(const int* __restrict__ edges, const int* __restrict__ off,
          const int* __restrict__ endv, const float* __restrict__ dinv,
          const __half* __restrict__ Yin, const float* __restrict__ Wn,
          const float* __restrict__ bias, void* __restrict__ Yout) {
    const uint2* __restrict__ Yin2 = (const uint2*)Yin;   // 16 × 8B per 64-half row
    int lane = threadIdx.x & 63;
    int q = lane & 15, s = lane >> 4;          // sub-group: s = which row of a quad
    int wid = blockIdx.x * 4 + (threadIdx.x >> 6);
    int n0 = wid * CPW;
    if (n0 >= N_NODES) return;
    float bb = bias[lane];
    float4 wc[16];
    if (!FINAL) {
#pragma unroll
        for (int t = 0; t < 16; ++t) {
            wc[t].x = Wn[(4 * t + 0) * 64 + lane];
            wc[t].y = Wn[(4 * t + 1) * 64 + lane];
            wc[t].z = Wn[(4 * t + 2) * 64 + lane];
            wc[t].w = Wn[(4 * t + 3) * 64 + lane];
        }
#pragma unroll
        for (int t = 0; t < 16; ++t) {
            asm volatile("" : "+v"(wc[t].x), "+v"(wc[t].y), "+v"(wc[t].z), "+v"(wc[t].w));
        }
    }
    // chunk metadata in lanes 0..15
    int mo = 0, me = 0; float md = 0.0f;
    if (lane < CPW) {
        int nn = n0 + lane;
        mo = off[nn]; me = endv[nn]; md = dinv[nn];
    }
    int j0 = rdli(mo, 0);
    int j1 = rdli(me, 0);
    int m0 = j1 - j0; if (m0 > 64) m0 = 64;
    int idx = j0 + lane; if (idx > N_EDGES - 1) idx = N_EDGES - 1;
    int ev = edges[idx];                         // edge-index vector, node 0
    uint2 sraw = make_uint2(0u, 0u);
    if (s == 0) sraw = Yin2[(size_t)n0 * 16 + q];   // self row (prescaled fp16)
    // prologue: prefetch node 0's first-32-edge rows (group guards wave-uniform)
    uint2 r0 = make_uint2(0u, 0u), r1 = r0, r2 = r0, r3 = r0;
    uint2 r4 = r0, r5 = r0, r6 = r0, r7 = r0;
    {
        int i0 = __shfl(ev, 0 + s, 64);
        int i1 = __shfl(ev, 4 + s, 64);
        int i2 = __shfl(ev, 8 + s, 64);
        int i3 = __shfl(ev, 12 + s, 64);
        int i4 = __shfl(ev, 16 + s, 64);
        int i5 = __shfl(ev, 20 + s, 64);
        int i6 = __shfl(ev, 24 + s, 64);
        int i7 = __shfl(ev, 28 + s, 64);
        if (m0 > 0)  r0 = Yin2[(size_t)i0 * 16 + q];
        if (m0 > 4)  r1 = Yin2[(size_t)i1 * 16 + q];
        if (m0 > 8)  r2 = Yin2[(size_t)i2 * 16 + q];
        if (m0 > 12) r3 = Yin2[(size_t)i3 * 16 + q];
        if (m0 > 16) r4 = Yin2[(size_t)i4 * 16 + q];
        if (m0 > 20) r5 = Yin2[(size_t)i5 * 16 + q];
        if (m0 > 24) r6 = Yin2[(size_t)i6 * 16 + q];
        if (m0 > 28) r7 = Yin2[(size_t)i7 * 16 + q];
    }
    for (int i = 0; i < CPW; ++i) {
        int n = n0 + i;
        float dn = rdlf(md, i);
        int deg = rdli(me, i) - j0;
        int m = m0;
        // next node's metadata + edge vector + self row (issue early)
        int evn = 0; int j0n = 0; int mn = 0;
        uint2 srn = make_uint2(0u, 0u);
        if (i < CPW - 1) {
            j0n = rdli(mo, i + 1);
            int j1n = rdli(me, i + 1);
            mn = j1n - j0n; if (mn > 64) mn = 64;
            int idn = j0n + lane; if (idn > N_EDGES - 1) idn = N_EDGES - 1;
            evn = edges[idn];
            if (s == 0) srn = Yin2[(size_t)(n + 1) * 16 + q];
        }
        // ---- accumulate prefetched first-32 rows (per-lane slot mask) ----
        float4 acc = make_float4(0.f, 0.f, 0.f, 0.f);
        if (s == 0) acc4h(acc, sraw);
        if (0 + s < m)  acc4h(acc, r0);
        if (4 + s < m)  acc4h(acc, r1);
        if (8 + s < m)  acc4h(acc, r2);
        if (12 + s < m) acc4h(acc, r3);
        if (16 + s < m) acc4h(acc, r4);
        if (20 + s < m) acc4h(acc, r5);
        if (24 + s < m) acc4h(acc, r6);
        if (28 + s < m) acc4h(acc, r7);
        // ---- remainder 32..m in-line (uniform group bound, per-lane mask) ----
        for (int t = 8; 4 * t < m; ++t) {
            int sl = 4 * t + s;
            int ii = __shfl(ev, sl, 64);
            uint2 rr = Yin2[(size_t)ii * 16 + q];
            if (sl < m) acc4h(acc, rr);
        }
        // ---- rare deg>64 tail (sub 0 only) ----
        for (int jj = 64; jj < deg; ++jj) {
            int sidx = edges[j0 + jj];
            if (s == 0) {
                uint2 rr = Yin2[(size_t)sidx * 16 + q];
                acc4h(acc, rr);
            }
        }
        // ---- PREFETCH next node's rows: results not used until next iter,
        //      so the vmcnt wait lands after the transform below ----
        if (i < CPW - 1) {
            int i0 = __shfl(evn, 0 + s, 64);
            int i1 = __shfl(evn, 4 + s, 64);
            int i2 = __shfl(evn, 8 + s, 64);
            int i3 = __shfl(evn, 12 + s, 64);
            int i4 = __shfl(evn, 16 + s, 64);
            int i5 = __shfl(evn, 20 + s, 64);
            int i6 = __shfl(evn, 24 + s, 64);
            int i7 = __shfl(evn, 28 + s, 64);
            r0 = make_uint2(0u, 0u); r1 = r0; r2 = r0; r3 = r0;
            r4 = r0; r5 = r0; r6 = r0; r7 = r0;
            if (mn > 0)  r0 = Yin2[(size_t)i0 * 16 + q];
            if (mn > 4)  r1 = Yin2[(size_t)i1 * 16 + q];
            if (mn > 8)  r2 = Yin2[(size_t)i2 * 16 + q];
            if (mn > 12) r3 = Yin2[(size_t)i3 * 16 + q];
            if (mn > 16) r4 = Yin2[(size_t)i4 * 16 + q];
            if (mn > 20) r5 = Yin2[(size_t)i5 * 16 + q];
            if (mn > 24) r6 = Yin2[(size_t)i6 * 16 + q];
            if (mn > 28) r7 = Yin2[(size_t)i7 * 16 + q];
        }
        // ---- combine the 4 sub-groups (long VALU stretch covers prefetch) ----
        acc.x += __shfl_xor(acc.x, 16, 64); acc.x += __shfl_xor(acc.x, 32, 64);
        acc.y += __shfl_xor(acc.y, 16, 64); acc.y += __shfl_xor(acc.y, 32, 64);
        acc.z += __shfl_xor(acc.z, 16, 64); acc.z += __shfl_xor(acc.z, 32, 64);
        acc.w += __shfl_xor(acc.w, 16, 64); acc.w += __shfl_xor(acc.w, 32, 64);
        // redistribute: channel-per-lane layout
        int srcl = lane >> 2;
        float c0 = __shfl(acc.x, srcl, 64);
        float c1 = __shfl(acc.y, srcl, 64);
        float c2 = __shfl(acc.z, srcl, 64);
        float c3 = __shfl(acc.w, srcl, 64);
        float lo = (lane & 1) ? c1 : c0;
        float hi = (lane & 1) ? c3 : c2;
        float sumc = (lane & 2) ? hi : lo;
        float h = dn * sumc + bb;
        h = h > 0.0f ? h : 0.0f;
        if (FINAL) {
            ((float*)Yout)[n * 64 + lane] = h;
        } else {
            float y0 = 0.0f, y1 = 0.0f, y2 = 0.0f, y3 = 0.0f;
#pragma unroll
            for (int t2 = 0; t2 < 16; ++t2) {
                float4 w = wc[t2];
                y0 = fmaf(rdlf(h, 4 * t2 + 0), w.x, y0);
                y1 = fmaf(rdlf(h, 4 * t2 + 1), w.y, y1);
                y2 = fmaf(rdlf(h, 4 * t2 + 2), w.z, y2);
                y3 = fmaf(rdlf(h, 4 * t2 + 3), w.w, y3);
            }
            ((__half*)Yout)[n * 64 + lane] = __float2half(dn * ((y0 + y1) + (y2 + y3)));
        }
        ev = evn; sraw = srn; j0 = j0n; m0 = mn;
    }
}

// ---------- segmented mean-pool accumulation (batch is sorted) ----------
#define PCHUNK 64
__global__ void k_pool(const float* __restrict__ A, const int* __restrict__ batch,
                       float* __restrict__ sums, float* __restrict__ cnts) {
    int c = threadIdx.x;
    int n0 = blockIdx.x * PCHUNK;
    int n1 = n0 + PCHUNK; if (n1 > N_NODES) n1 = N_NODES;
    int gcur = batch[n0];
    float acc = 0.0f;
    int cnt = 0;
    for (int n = n0; n < n1; ++n) {
        int g = batch[n];
        if (g != gcur) {
            atomicAdd(&sums[gcur * 64 + c], acc);
            if (c == 0) atomicAdd(&cnts[gcur], (float)cnt);
            acc = 0.0f; cnt = 0; gcur = g;
        }
        acc += A[n * 64 + c];
        ++cnt;
    }
    atomicAdd(&sums[gcur * 64 + c], acc);
    if (c == 0) atomicAdd(&cnts[gcur], (float)cnt);
}

// ---------- MLP head ----------
__global__ void k_head(const float* __restrict__ sums, const float* __restrict__ cnts,
                       const float* __restrict__ Wf1, const float* __restrict__ bf1,
                       const float* __restrict__ Wf2, const float* __restrict__ bf2,
                       float* __restrict__ out) {
    __shared__ float p[64];
    __shared__ float h[64];
    int g = blockIdx.x;
    int c = threadIdx.x;
    float cnt = cnts[g];
    cnt = cnt > 1.0f ? cnt : 1.0f;
    p[c] = sums[g * 64 + c] / cnt;
    __syncthreads();
    float s = bf1[c];
#pragma unroll
    for (int k = 0; k < 64; ++k) s += p[k] * Wf1[k * 64 + c];
    h[c] = s > 0.0f ? s : 0.0f;
    __syncthreads();
    if (c < N_CLASSES) {
        float o = bf2[c];
#pragma unroll
        for (int k = 0; k < 64; ++k) o += h[k] * Wf2[k * N_CLASSES + c];
        out[g * N_CLASSES + c] = o;
    }
}

extern "C" void kernel_launch(void* const* d_in, const int* in_sizes, int n_in,
                              void* d_out, int out_size, void* d_ws, size_t ws_size,
                              hipStream_t stream) {
    const float* x   = (const float*)d_in[0];
    const int*   ei  = (const int*)d_in[1];
    const int*   bat = (const int*)d_in[2];
    const float* W1  = (const float*)d_in[3];
    const float* b1  = (const float*)d_in[4];
    const float* W2  = (const float*)d_in[5];
    const float* b2  = (const float*)d_in[6];
    const float* W3  = (const float*)d_in[7];
    const float* b3  = (const float*)d_in[8];
    const float* Wf1 = (const float*)d_in[9];
    const float* bf1 = (const float*)d_in[10];
    const float* Wf2 = (const float*)d_in[11];
    const float* bf2 = (const float*)d_in[12];
    float* out = (float*)d_out;

    const int* src = ei;
    const int* dst = ei + N_EDGES;

    char* p = (char*)d_ws;
    float*  A    = (float*)p;   p += (size_t)N_NODES * 64 * 4;   // fp32 final acts
    __half* Ph   = (__half*)p;  p += (size_t)N_NODES * 64 * 2;   // fp16 prescaled (post-L1)
    __half* Qh   = (__half*)p;  p += (size_t)N_NODES * 64 * 2;   // fp16 prescaled (post-L2)
    int*   stage = (int*)p;     p += (size_t)N_EDGES * 4;
    int*   edges = (int*)p;     p += (size_t)N_EDGES * 4;
    int*   off   = (int*)p;     p += (size_t)N_NODES * 4;
    int*   endv  = (int*)p;     p += (size_t)N_NODES * 4;
    float* dinv  = (float*)p;   p += (size_t)N_NODES * 4;
    float* xs2   = (float*)p;   p += (size_t)N_NODES * 2 * 4;
    int*   chist = (int*)p;     p += (size_t)256 * 4;
    int*   cbase = (int*)p;     p += (size_t)256 * 4;
    int*   gcur  = (int*)p;     p += (size_t)256 * 4;
    float* sums  = (float*)p;   p += (size_t)N_GRAPHS * 64 * 4;
    float* cnts  = (float*)p;   p += (size_t)N_GRAPHS * 4;

    hipMemsetAsync(chist, 0, 256 * 4, stream);
    hipMemsetAsync(sums, 0, (size_t)(N_GRAPHS * 64 + N_GRAPHS) * 4, stream);

    const int BT = 256;
    int gChist = (N_EDGES + 256 * CH_EPT - 1) / (256 * CH_EPT);   // 782
    int gPart  = (N_EDGES + 256 * PT_EPT - 1) / (256 * PT_EPT);   // 391

    // ---- CSR build (binned, no global scatter over full buffer) ----
    k_chist<<<gChist, BT, 0, stream>>>(dst, chist);
    k_cscan<<<1, 256, 0, stream>>>(chist, cbase, gcur);
    k_part<<<gPart, BT, 0, stream>>>(src, dst, gcur, stage);
    k_sort<<<NBUCK, 256, 0, stream>>>(stage, cbase, edges, off, endv, dinv,
                                      (const float2*)x, (float2*)xs2);

    // ---- layer 1 (gather x, W1, relu, fused W2 transform + prescale, fp16 out) ----
    k_l1<<<GLAYER, BT, 0, stream>>>(edges, off, endv, dinv, (const float2*)xs2,
                                    W1, b1, W2, Ph);

    // ---- layer 2 (pipelined fp16 quad gather + b2/relu + fused W3, fp16 out) ----
    k_gl<false><<<GLAYER, BT, 0, stream>>>(edges, off, endv, dinv, Ph, W3, b2, Qh);

    // ---- layer 3 (pipelined fp16 quad gather + b3/relu, fp32 final acts) ----
    k_gl<true><<<GLAYER, BT, 0, stream>>>(edges, off, endv, dinv, Qh, nullptr, b3, A);

    // ---- pool + head ----
    k_pool<<<(N_NODES + PCHUNK - 1) / PCHUNK, 64, 0, stream>>>(A, bat, sums, cnts);
    k_head<<<N_GRAPHS, 64, 0, stream>>>(sums, cnts, Wf1, bf1, Wf2, bf2, out);
}

// Round 14
// 459.622 us; speedup vs baseline: 1.2810x; 1.0161x over previous
//
#include <hip/hip_runtime.h>
#include <hip/hip_fp16.h>

#define N_NODES  200000
#define N_EDGES  3200000
#define HIDDEN   64
#define N_GRAPHS 4096
#define N_CLASSES 7
#define NBUCK    196          // ceil(N_NODES / 1024)
#define BSHIFT   10
#define BMASK    1023
#define CPW      16           // nodes (chunk) per wave
#define NCHUNK   (N_NODES / CPW)          // 12500
#define GLAYER   (NCHUNK / 4)             // 3125 blocks of 4 waves

// ---------- coarse histogram (196 buckets) ----------
#define CH_EPT 16
__global__ void k_chist(const int* __restrict__ dst, int* __restrict__ chist) {
    __shared__ int h[NBUCK];
    for (int i = threadIdx.x; i < NBUCK; i += 256) h[i] = 0;
    __syncthreads();
    int base = blockIdx.x * 256 * CH_EPT + threadIdx.x;
    for (int k = 0; k < CH_EPT; ++k) {
        int e = base + k * 256;
        if (e < N_EDGES) atomicAdd(&h[dst[e] >> BSHIFT], 1);
    }
    __syncthreads();
    for (int i = threadIdx.x; i < NBUCK; i += 256) atomicAdd(&chist[i], h[i]);
}

// ---------- scan of 196 bucket counts ----------
__global__ void k_cscan(const int* __restrict__ chist, int* __restrict__ cbase,
                        int* __restrict__ gcur) {
    __shared__ int tmp[256];
    int tid = threadIdx.x;
    int v = (tid < NBUCK) ? chist[tid] : 0;
    int x = v; tmp[tid] = x; __syncthreads();
    for (int o = 1; o < 256; o <<= 1) {
        int y = (tid >= o) ? tmp[tid - o] : 0;
        __syncthreads();
        x += y; tmp[tid] = x;
        __syncthreads();
    }
    if (tid < NBUCK) { cbase[tid] = x - v; gcur[tid] = x - v; }
    if (tid == 0) cbase[NBUCK] = N_EDGES;
}

// ---------- coarse partition, LDS-staged: block-local counting sort into LDS,
//            then bucket-contiguous (coalesced) global writes ----------
#define PT_EPT 32
#define PT_EDGES (256 * PT_EPT)           // 8192 edges per block
__global__ void k_part(const int* __restrict__ src, const int* __restrict__ dst,
                       int* __restrict__ gcur, int* __restrict__ stage) {
    __shared__ int lh[NBUCK];
    __shared__ int lofs[NBUCK];
    __shared__ int lbase[NBUCK];
    __shared__ int lcur[NBUCK];
    __shared__ int tmp[256];
    __shared__ int buf[PT_EDGES];         // 32 KB staged payloads
    __shared__ unsigned char bid[PT_EDGES];   // bucket id per staged slot
    int tid = threadIdx.x;
    for (int i = tid; i < NBUCK; i += 256) { lh[i] = 0; lcur[i] = 0; }
    __syncthreads();
    int base = blockIdx.x * PT_EDGES + tid;
    for (int k = 0; k < PT_EPT; ++k) {
        int e = base + k * 256;
        if (e < N_EDGES) atomicAdd(&lh[dst[e] >> BSHIFT], 1);
    }
    __syncthreads();
    // block scan of 196 bucket counts -> local offsets; reserve global ranges
    int v = (tid < NBUCK) ? lh[tid] : 0;
    int x = v; tmp[tid] = x; __syncthreads();
    for (int o = 1; o < 256; o <<= 1) {
        int y = (tid >= o) ? tmp[tid - o] : 0;
        __syncthreads();
        x += y; tmp[tid] = x;
        __syncthreads();
    }
    if (tid < NBUCK) {
        lofs[tid] = x - v;
        if (v > 0) lbase[tid] = atomicAdd(&gcur[tid], v);
    }
    __syncthreads();
    // scatter into LDS (cheap) instead of global
    for (int k = 0; k < PT_EPT; ++k) {
        int e = base + k * 256;
        if (e < N_EDGES) {
            int d = dst[e], b = d >> BSHIFT;
            int lp = lofs[b] + atomicAdd(&lcur[b], 1);
            buf[lp] = (src[e] << BSHIFT) | (d & BMASK);
            bid[lp] = (unsigned char)b;
        }
    }
    __syncthreads();
    // bucket-contiguous global writes (runs of ~42 edges -> coalesced)
    int nval = N_EDGES - blockIdx.x * PT_EDGES;
    if (nval > PT_EDGES) nval = PT_EDGES;
    for (int l = tid; l < nval; l += 256) {
        int b = bid[l];
        stage[lbase[b] + (l - lofs[b])] = buf[l];
    }
}

// ---------- per-bucket exact sort + CSR metadata; also prescale x by dinv ----------
__global__ void k_sort(const int* __restrict__ stage, const int* __restrict__ cbase,
                       int* __restrict__ edges, int* __restrict__ off,
                       int* __restrict__ endv, float* __restrict__ dinv,
                       const float2* __restrict__ x2, float2* __restrict__ xs2) {
    __shared__ int hist[1024];
    __shared__ int tmp[256];
    int b = blockIdx.x, tid = threadIdx.x;
    int cb0 = cbase[b], cb1 = cbase[b + 1];
    for (int k = 0; k < 4; ++k) hist[tid * 4 + k] = 0;
    __syncthreads();
    for (int j = cb0 + tid; j < cb1; j += 256)
        atomicAdd(&hist[stage[j] & BMASK], 1);
    __syncthreads();
    int c0 = hist[tid*4], c1 = hist[tid*4+1], c2 = hist[tid*4+2], c3 = hist[tid*4+3];
    int s = c0 + c1 + c2 + c3;
    int x = s; tmp[tid] = x; __syncthreads();
    for (int o = 1; o < 256; o <<= 1) {
        int y = (tid >= o) ? tmp[tid - o] : 0;
        __syncthreads();
        x += y; tmp[tid] = x;
        __syncthreads();
    }
    int run = x - s;                 // exclusive prefix of this thread's 4 counters
    int nbase = b << BSHIFT;
    int counts[4] = {c0, c1, c2, c3};
    for (int k = 0; k < 4; ++k) {
        int v = tid * 4 + k;
        hist[v] = run;               // local cursor start
        int node = nbase + v;
        if (node < N_NODES) {
            off[node]  = cb0 + run;
            endv[node] = cb0 + run + counts[k];
            float di = rsqrtf((float)counts[k] + 1.0f);   // +1 self loop
            dinv[node] = di;
            float2 xv = x2[node];
            xs2[node] = make_float2(di * xv.x, di * xv.y);
        }
        run += counts[k];
    }
    __syncthreads();
    for (int j = cb0 + tid; j < cb1; j += 256) {
        int p = stage[j];
        int pos = atomicAdd(&hist[p & BMASK], 1);
        edges[cb0 + pos] = p >> BSHIFT;     // src
    }
}

static __device__ __forceinline__ float rdlf(float v, int l) {
    return __uint_as_float(__builtin_amdgcn_readlane(__float_as_uint(v), (unsigned)l));
}
static __device__ __forceinline__ int rdli(int v, int l) {
    return __builtin_amdgcn_readlane(v, (unsigned)l);
}
// fp16 row fragment (4 channels) -> fp32 accumulate
static __device__ __forceinline__ void acc4h(float4& a, uint2 r) {
    __half2 h01 = *reinterpret_cast<const __half2*>(&r.x);
    __half2 h23 = *reinterpret_cast<const __half2*>(&r.y);
    float2 f01 = __half22float2(h01);
    float2 f23 = __half22float2(h23);
    a.x += f01.x; a.y += f01.y; a.z += f23.x; a.w += f23.y;
}

// ---------- layer 1: chunked gather of prescaled x (value-prefetched) + W1 +
//            relu + fused W2, store fp16 prescaled rows ----------
__global__ __launch_bounds__(256, 4)
void k_l1(const int* __restrict__ edges, const int* __restrict__ off,
          const int* __restrict__ endv, const float* __restrict__ dinv,
          const float2* __restrict__ xs2,
          const float* __restrict__ W1, const float* __restrict__ b1,
          const float* __restrict__ W2, __half* __restrict__ Yout) {
    int lane = threadIdx.x & 63;
    int wid = blockIdx.x * 4 + (threadIdx.x >> 6);
    int n0 = wid * CPW;
    if (n0 >= N_NODES) return;
    float w1a = W1[lane], w1b = W1[64 + lane], bb = b1[lane];
    float4 wc[16];
#pragma unroll
    for (int t = 0; t < 16; ++t) {
        wc[t].x = W2[(4 * t + 0) * 64 + lane];
        wc[t].y = W2[(4 * t + 1) * 64 + lane];
        wc[t].z = W2[(4 * t + 2) * 64 + lane];
        wc[t].w = W2[(4 * t + 3) * 64 + lane];
    }
#pragma unroll
    for (int t = 0; t < 16; ++t) {
        asm volatile("" : "+v"(wc[t].x), "+v"(wc[t].y), "+v"(wc[t].z), "+v"(wc[t].w));
    }
    // chunk metadata in lanes 0..15
    int mo = 0, me = 0; float md = 0.0f; float sxx = 0.0f, sxy = 0.0f;
    if (lane < CPW) {
        int nn = n0 + lane;
        mo = off[nn]; me = endv[nn]; md = dinv[nn];
        float2 sv = xs2[nn];
        sxx = sv.x; sxy = sv.y;
    }
    int j0 = rdli(mo, 0);
    int deg0 = rdli(me, 0) - j0;
    int idx = j0 + lane; if (idx > N_EDGES - 1) idx = N_EDGES - 1;
    int ev = edges[idx];
    float pxv = 0.0f, pyv = 0.0f;                // prefetched gather values
    if (lane < deg0) {
        float2 v = xs2[ev];
        pxv = v.x; pyv = v.y;
    }
    for (int i = 0; i < CPW; ++i) {
        int n = n0 + i;
        float dn = rdlf(md, i);
        int deg = rdli(me, i) - j0;
        // prefetch next node's edge vector AND its gather values
        int evn = 0; int j0n = 0;
        float pxn = 0.0f, pyn = 0.0f;
        if (i < CPW - 1) {
            j0n = rdli(mo, i + 1);
            int degn = rdli(me, i + 1) - j0n;
            int idn = j0n + lane; if (idn > N_EDGES - 1) idn = N_EDGES - 1;
            evn = edges[idn];
            if (lane < degn) {
                float2 v = xs2[evn];
                pxn = v.x; pyn = v.y;
            }
        }
        float px = pxv, py = pyv;
        for (int jj = j0 + 64 + lane; jj < j0 + deg; jj += 64) {   // rare deg>64 tail
            float2 v = xs2[edges[jj]];
            px += v.x; py += v.y;
        }
#pragma unroll
        for (int o = 1; o < 64; o <<= 1) {
            px += __shfl_xor(px, o, 64);
            py += __shfl_xor(py, o, 64);
        }
        float gx = dn * (px + rdlf(sxx, i));
        float gy = dn * (py + rdlf(sxy, i));
        float h = gx * w1a + gy * w1b + bb;
        h = h > 0.0f ? h : 0.0f;
        float y0 = 0.0f, y1 = 0.0f, y2 = 0.0f, y3 = 0.0f;
#pragma unroll
        for (int t = 0; t < 16; ++t) {
            float4 w = wc[t];
            y0 = fmaf(rdlf(h, 4 * t + 0), w.x, y0);
            y1 = fmaf(rdlf(h, 4 * t + 1), w.y, y1);
            y2 = fmaf(rdlf(h, 4 * t + 2), w.z, y2);
            y3 = fmaf(rdlf(h, 4 * t + 3), w.w, y3);
        }
        Yout[n * 64 + lane] = __float2half(dn * ((y0 + y1) + (y2 + y3)));
        ev = evn; j0 = j0n; pxv = pxn; pyv = pyn;
    }
}

// ---------- layers 2/3: software-pipelined quad-row fp16 gather, 32-slot
//            prefetch (group-guarded, no waste): node i+1's first-32-edge
//            rows issue BEFORE node i's reduce+transform ----------
template<bool FINAL>
__global__ __launch_bounds__(256, 4)
void k_gl(const int* __restrict__ edges, const int* __restrict__ off,
          const int* __restrict__ endv, const float* __restrict__ dinv,
          const __half* __restrict__ Yin, const float* __restrict__ Wn,
          const float* __restrict__ bias, void* __restrict__ Yout) {
    const uint2* __restrict__ Yin2 = (const uint2*)Yin;   // 16 × 8B per 64-half row
    int lane = threadIdx.x & 63;
    int q = lane & 15, s = lane >> 4;          // sub-group: s = which row of a quad
    int wid = blockIdx.x * 4 + (threadIdx.x >> 6);
    int n0 = wid * CPW;
    if (n0 >= N_NODES) return;
    float bb = bias[lane];
    float4 wc[16];
    if (!FINAL) {
#pragma unroll
        for (int t = 0; t < 16; ++t) {
            wc[t].x = Wn[(4 * t + 0) * 64 + lane];
            wc[t].y = Wn[(4 * t + 1) * 64 + lane];
            wc[t].z = Wn[(4 * t + 2) * 64 + lane];
            wc[t].w = Wn[(4 * t + 3) * 64 + lane];
        }
#pragma unroll
        for (int t = 0; t < 16; ++t) {
            asm volatile("" : "+v"(wc[t].x), "+v"(wc[t].y), "+v"(wc[t].z), "+v"(wc[t].w));
        }
    }
    // chunk metadata in lanes 0..15
    int mo = 0, me = 0; float md = 0.0f;
    if (lane < CPW) {
        int nn = n0 + lane;
        mo = off[nn]; me = endv[nn]; md = dinv[nn];
    }
    int j0 = rdli(mo, 0);
    int j1 = rdli(me, 0);
    int m0 = j1 - j0; if (m0 > 64) m0 = 64;
    int idx = j0 + lane; if (idx > N_EDGES - 1) idx = N_EDGES - 1;
    int ev = edges[idx];                         // edge-index vector, node 0
    uint2 sraw = make_uint2(0u, 0u);
    if (s == 0) sraw = Yin2[(size_t)n0 * 16 + q];   // self row (prescaled fp16)
    // prologue: prefetch node 0's first-32-edge rows (group guards wave-uniform)
    uint2 r0 = make_uint2(0u, 0u), r1 = r0, r2 = r0, r3 = r0;
    uint2 r4 = r0, r5 = r0, r6 = r0, r7 = r0;
    {
        int i0 = __shfl(ev, 0 + s, 64);
        int i1 = __shfl(ev, 4 + s, 64);
        int i2 = __shfl(ev, 8 + s, 64);
        int i3 = __shfl(ev, 12 + s, 64);
        int i4 = __shfl(ev, 16 + s, 64);
        int i5 = __shfl(ev, 20 + s, 64);
        int i6 = __shfl(ev, 24 + s, 64);
        int i7 = __shfl(ev, 28 + s, 64);
        if (m0 > 0)  r0 = Yin2[(size_t)i0 * 16 + q];
        if (m0 > 4)  r1 = Yin2[(size_t)i1 * 16 + q];
        if (m0 > 8)  r2 = Yin2[(size_t)i2 * 16 + q];
        if (m0 > 12) r3 = Yin2[(size_t)i3 * 16 + q];
        if (m0 > 16) r4 = Yin2[(size_t)i4 * 16 + q];
        if (m0 > 20) r5 = Yin2[(size_t)i5 * 16 + q];
        if (m0 > 24) r6 = Yin2[(size_t)i6 * 16 + q];
        if (m0 > 28) r7 = Yin2[(size_t)i7 * 16 + q];
    }
    for (int i = 0; i < CPW; ++i) {
        int n = n0 + i;
        float dn = rdlf(md, i);
        int deg = rdli(me, i) - j0;
        int m = m0;
        // next node's metadata + edge vector + self row (issue early)
        int evn = 0; int j0n = 0; int mn = 0;
        uint2 srn = make_uint2(0u, 0u);
        if (i < CPW - 1) {
            j0n = rdli(mo, i + 1);
            int j1n = rdli(me, i + 1);
            mn = j1n - j0n; if (mn > 64) mn = 64;
            int idn = j0n + lane; if (idn > N_EDGES - 1) idn = N_EDGES - 1;
            evn = edges[idn];
            if (s == 0) srn = Yin2[(size_t)(n + 1) * 16 + q];
        }
        // ---- accumulate prefetched first-32 rows (per-lane slot mask) ----
        float4 acc = make_float4(0.f, 0.f, 0.f, 0.f);
        if (s == 0) acc4h(acc, sraw);
        if (0 + s < m)  acc4h(acc, r0);
        if (4 + s < m)  acc4h(acc, r1);
        if (8 + s < m)  acc4h(acc, r2);
        if (12 + s < m) acc4h(acc, r3);
        if (16 + s < m) acc4h(acc, r4);
        if (20 + s < m) acc4h(acc, r5);
        if (24 + s < m) acc4h(acc, r6);
        if (28 + s < m) acc4h(acc, r7);
        // ---- remainder 32..m in-line (uniform group bound, per-lane mask) ----
        for (int t = 8; 4 * t < m; ++t) {
            int sl = 4 * t + s;
            int ii = __shfl(ev, sl, 64);
            uint2 rr = Yin2[(size_t)ii * 16 + q];
            if (sl < m) acc4h(acc, rr);
        }
        // ---- rare deg>64 tail (sub 0 only) ----
        for (int jj = 64; jj < deg; ++jj) {
            int sidx = edges[j0 + jj];
            if (s == 0) {
                uint2 rr = Yin2[(size_t)sidx * 16 + q];
                acc4h(acc, rr);
            }
        }
        // ---- PREFETCH next node's rows: results not used until next iter,
        //      so the vmcnt wait lands after the transform below ----
        if (i < CPW - 1) {
            int i0 = __shfl(evn, 0 + s, 64);
            int i1 = __shfl(evn, 4 + s, 64);
            int i2 = __shfl(evn, 8 + s, 64);
            int i3 = __shfl(evn, 12 + s, 64);
            int i4 = __shfl(evn, 16 + s, 64);
            int i5 = __shfl(evn, 20 + s, 64);
            int i6 = __shfl(evn, 24 + s, 64);
            int i7 = __shfl(evn, 28 + s, 64);
            r0 = make_uint2(0u, 0u); r1 = r0; r2 = r0; r3 = r0;
            r4 = r0; r5 = r0; r6 = r0; r7 = r0;
            if (mn > 0)  r0 = Yin2[(size_t)i0 * 16 + q];
            if (mn > 4)  r1 = Yin2[(size_t)i1 * 16 + q];
            if (mn > 8)  r2 = Yin2[(size_t)i2 * 16 + q];
            if (mn > 12) r3 = Yin2[(size_t)i3 * 16 + q];
            if (mn > 16) r4 = Yin2[(size_t)i4 * 16 + q];
            if (mn > 20) r5 = Yin2[(size_t)i5 * 16 + q];
            if (mn > 24) r6 = Yin2[(size_t)i6 * 16 + q];
            if (mn > 28) r7 = Yin2[(size_t)i7 * 16 + q];
        }
        // ---- combine the 4 sub-groups (long VALU stretch covers prefetch) ----
        acc.x += __shfl_xor(acc.x, 16, 64); acc.x += __shfl_xor(acc.x, 32, 64);
        acc.y += __shfl_xor(acc.y, 16, 64); acc.y += __shfl_xor(acc.y, 32, 64);
        acc.z += __shfl_xor(acc.z, 16, 64); acc.z += __shfl_xor(acc.z, 32, 64);
        acc.w += __shfl_xor(acc.w, 16, 64); acc.w += __shfl_xor(acc.w, 32, 64);
        // redistribute: channel-per-lane layout
        int srcl = lane >> 2;
        float c0 = __shfl(acc.x, srcl, 64);
        float c1 = __shfl(acc.y, srcl, 64);
        float c2 = __shfl(acc.z, srcl, 64);
        float c3 = __shfl(acc.w, srcl, 64);
        float lo = (lane & 1) ? c1 : c0;
        float hi = (lane & 1) ? c3 : c2;
        float sumc = (lane & 2) ? hi : lo;
        float h = dn * sumc + bb;
        h = h > 0.0f ? h : 0.0f;
        if (FINAL) {
            ((float*)Yout)[n * 64 + lane] = h;
        } else {
            float y0 = 0.0f, y1 = 0.0f, y2 = 0.0f, y3 = 0.0f;
#pragma unroll
            for (int t2 = 0; t2 < 16; ++t2) {
                float4 w = wc[t2];
                y0 = fmaf(rdlf(h, 4 * t2 + 0), w.x, y0);
                y1 = fmaf(rdlf(h, 4 * t2 + 1), w.y, y1);
                y2 = fmaf(rdlf(h, 4 * t2 + 2), w.z, y2);
                y3 = fmaf(rdlf(h, 4 * t2 + 3), w.w, y3);
            }
            ((__half*)Yout)[n * 64 + lane] = __float2half(dn * ((y0 + y1) + (y2 + y3)));
        }
        ev = evn; sraw = srn; j0 = j0n; m0 = mn;
    }
}

// ---------- segmented mean-pool accumulation (batch is sorted) ----------
#define PCHUNK 64
__global__ void k_pool(const float* __restrict__ A, const int* __restrict__ batch,
                       float* __restrict__ sums, float* __restrict__ cnts) {
    int c = threadIdx.x;
    int n0 = blockIdx.x * PCHUNK;
    int n1 = n0 + PCHUNK; if (n1 > N_NODES) n1 = N_NODES;
    int gcur = batch[n0];
    float acc = 0.0f;
    int cnt = 0;
    for (int n = n0; n < n1; ++n) {
        int g = batch[n];
        if (g != gcur) {
            atomicAdd(&sums[gcur * 64 + c], acc);
            if (c == 0) atomicAdd(&cnts[gcur], (float)cnt);
            acc = 0.0f; cnt = 0; gcur = g;
        }
        acc += A[n * 64 + c];
        ++cnt;
    }
    atomicAdd(&sums[gcur * 64 + c], acc);
    if (c == 0) atomicAdd(&cnts[gcur], (float)cnt);
}

// ---------- MLP head ----------
__global__ void k_head(const float* __restrict__ sums, const float* __restrict__ cnts,
                       const float* __restrict__ Wf1, const float* __restrict__ bf1,
                       const float* __restrict__ Wf2, const float* __restrict__ bf2,
                       float* __restrict__ out) {
    __shared__ float p[64];
    __shared__ float h[64];
    int g = blockIdx.x;
    int c = threadIdx.x;
    float cnt = cnts[g];
    cnt = cnt > 1.0f ? cnt : 1.0f;
    p[c] = sums[g * 64 + c] / cnt;
    __syncthreads();
    float s = bf1[c];
#pragma unroll
    for (int k = 0; k < 64; ++k) s += p[k] * Wf1[k * 64 + c];
    h[c] = s > 0.0f ? s : 0.0f;
    __syncthreads();
    if (c < N_CLASSES) {
        float o = bf2[c];
#pragma unroll
        for (int k = 0; k < 64; ++k) o += h[k] * Wf2[k * N_CLASSES + c];
        out[g * N_CLASSES + c] = o;
    }
}

extern "C" void kernel_launch(void* const* d_in, const int* in_sizes, int n_in,
                              void* d_out, int out_size, void* d_ws, size_t ws_size,
                              hipStream_t stream) {
    const float* x   = (const float*)d_in[0];
    const int*   ei  = (const int*)d_in[1];
    const int*   bat = (const int*)d_in[2];
    const float* W1  = (const float*)d_in[3];
    const float* b1  = (const float*)d_in[4];
    const float* W2  = (const float*)d_in[5];
    const float* b2  = (const float*)d_in[6];
    const float* W3  = (const float*)d_in[7];
    const float* b3  = (const float*)d_in[8];
    const float* Wf1 = (const float*)d_in[9];
    const float* bf1 = (const float*)d_in[10];
    const float* Wf2 = (const float*)d_in[11];
    const float* bf2 = (const float*)d_in[12];
    float* out = (float*)d_out;

    const int* src = ei;
    const int* dst = ei + N_EDGES;

    char* p = (char*)d_ws;
    float*  A    = (float*)p;   p += (size_t)N_NODES * 64 * 4;   // fp32 final acts
    __half* Ph   = (__half*)p;  p += (size_t)N_NODES * 64 * 2;   // fp16 prescaled (post-L1)
    __half* Qh   = (__half*)p;  p += (size_t)N_NODES * 64 * 2;   // fp16 prescaled (post-L2)
    int*   stage = (int*)p;     p += (size_t)N_EDGES * 4;
    int*   edges = (int*)p;     p += (size_t)N_EDGES * 4;
    int*   off   = (int*)p;     p += (size_t)N_NODES * 4;
    int*   endv  = (int*)p;     p += (size_t)N_NODES * 4;
    float* dinv  = (float*)p;   p += (size_t)N_NODES * 4;
    float* xs2   = (float*)p;   p += (size_t)N_NODES * 2 * 4;
    int*   chist = (int*)p;     p += (size_t)256 * 4;
    int*   cbase = (int*)p;     p += (size_t)256 * 4;
    int*   gcur  = (int*)p;     p += (size_t)256 * 4;
    float* sums  = (float*)p;   p += (size_t)N_GRAPHS * 64 * 4;
    float* cnts  = (float*)p;   p += (size_t)N_GRAPHS * 4;

    hipMemsetAsync(chist, 0, 256 * 4, stream);
    hipMemsetAsync(sums, 0, (size_t)(N_GRAPHS * 64 + N_GRAPHS) * 4, stream);

    const int BT = 256;
    int gChist = (N_EDGES + 256 * CH_EPT - 1) / (256 * CH_EPT);   // 782
    int gPart  = (N_EDGES + PT_EDGES - 1) / PT_EDGES;             // 391

    // ---- CSR build (binned, LDS-staged partition, coalesced writes) ----
    k_chist<<<gChist, BT, 0, stream>>>(dst, chist);
    k_cscan<<<1, 256, 0, stream>>>(chist, cbase, gcur);
    k_part<<<gPart, BT, 0, stream>>>(src, dst, gcur, stage);
    k_sort<<<NBUCK, 256, 0, stream>>>(stage, cbase, edges, off, endv, dinv,
                                      (const float2*)x, (float2*)xs2);

    // ---- layer 1 (pipelined gather x, W1, relu, fused W2 + prescale, fp16 out) ----
    k_l1<<<GLAYER, BT, 0, stream>>>(edges, off, endv, dinv, (const float2*)xs2,
                                    W1, b1, W2, Ph);

    // ---- layer 2 (pipelined fp16 quad gather + b2/relu + fused W3, fp16 out) ----
    k_gl<false><<<GLAYER, BT, 0, stream>>>(edges, off, endv, dinv, Ph, W3, b2, Qh);

    // ---- layer 3 (pipelined fp16 quad gather + b3/relu, fp32 final acts) ----
    k_gl<true><<<GLAYER, BT, 0, stream>>>(edges, off, endv, dinv, Qh, nullptr, b3, A);

    // ---- pool + head ----
    k_pool<<<(N_NODES + PCHUNK - 1) / PCHUNK, 64, 0, stream>>>(A, bat, sums, cnts);
    k_head<<<N_GRAPHS, 64, 0, stream>>>(sums, cnts, Wf1, bf1, Wf2, bf2, out);
}

// Round 17
// 438.175 us; speedup vs baseline: 1.3437x; 1.0489x over previous
//
#include <hip/hip_runtime.h>
#include <hip/hip_fp16.h>

#define N_NODES  200000
#define N_EDGES  3200000
#define HIDDEN   64
#define N_GRAPHS 4096
#define N_CLASSES 7
#define NBUCK    196          // ceil(N_NODES / 1024)
#define BSHIFT   10
#define BMASK    1023
#define BCAP     18432        // fixed bucket capacity (E=16384, sigma~128, 16-sigma margin)
#define CPW      16           // nodes (chunk) per wave
#define NCHUNK   (N_NODES / CPW)          // 12500
#define GLAYER   (NCHUNK / 4)             // 3125 blocks of 4 waves

// ---------- init per-bucket cursors to fixed slot bases ----------
__global__ void k_init(int* __restrict__ gcur) {
    int tid = threadIdx.x;
    if (tid < NBUCK) gcur[tid] = tid * BCAP;
}

// ---------- coarse partition, LDS-staged: block-local counting sort into LDS,
//            then bucket-contiguous (coalesced) global writes into fixed slots ----------
#define PT_EPT 32
#define PT_EDGES (256 * PT_EPT)           // 8192 edges per block
__global__ void k_part(const int* __restrict__ src, const int* __restrict__ dst,
                       int* __restrict__ gcur, int* __restrict__ stage) {
    __shared__ int lh[NBUCK];
    __shared__ int lofs[NBUCK];
    __shared__ int lbase[NBUCK];
    __shared__ int lcur[NBUCK];
    __shared__ int tmp[256];
    __shared__ int buf[PT_EDGES];         // 32 KB staged payloads
    __shared__ unsigned char bid[PT_EDGES];   // bucket id per staged slot
    int tid = threadIdx.x;
    for (int i = tid; i < NBUCK; i += 256) { lh[i] = 0; lcur[i] = 0; }
    __syncthreads();
    int base = blockIdx.x * PT_EDGES + tid;
    for (int k = 0; k < PT_EPT; ++k) {
        int e = base + k * 256;
        if (e < N_EDGES) atomicAdd(&lh[dst[e] >> BSHIFT], 1);
    }
    __syncthreads();
    // block scan of 196 bucket counts -> local offsets; reserve global ranges
    int v = (tid < NBUCK) ? lh[tid] : 0;
    int x = v; tmp[tid] = x; __syncthreads();
    for (int o = 1; o < 256; o <<= 1) {
        int y = (tid >= o) ? tmp[tid - o] : 0;
        __syncthreads();
        x += y; tmp[tid] = x;
        __syncthreads();
    }
    if (tid < NBUCK) {
        lofs[tid] = x - v;
        if (v > 0) lbase[tid] = atomicAdd(&gcur[tid], v);
    }
    __syncthreads();
    // scatter into LDS (cheap) instead of global
    for (int k = 0; k < PT_EPT; ++k) {
        int e = base + k * 256;
        if (e < N_EDGES) {
            int d = dst[e], b = d >> BSHIFT;
            int lp = lofs[b] + atomicAdd(&lcur[b], 1);
            buf[lp] = (src[e] << BSHIFT) | (d & BMASK);
            bid[lp] = (unsigned char)b;
        }
    }
    __syncthreads();
    // bucket-contiguous global writes (runs of ~42 edges -> coalesced)
    int nval = N_EDGES - blockIdx.x * PT_EDGES;
    if (nval > PT_EDGES) nval = PT_EDGES;
    for (int l = tid; l < nval; l += 256) {
        int b = bid[l];
        stage[lbase[b] + (l - lofs[b])] = buf[l];
    }
}

// ---------- per-bucket exact sort + CSR metadata; also prescale x by dinv.
//            ZERO-FILLS the bucket gap so downstream over-reads see valid
//            node index 0 (masked out of sums, but in-bounds). ----------
__global__ void k_sort(const int* __restrict__ stage, const int* __restrict__ gcur,
                       int* __restrict__ edges, int* __restrict__ off,
                       int* __restrict__ endv, float* __restrict__ dinv,
                       const float2* __restrict__ x2, float2* __restrict__ xs2) {
    __shared__ int hist[1024];
    __shared__ int tmp[256];
    int b = blockIdx.x, tid = threadIdx.x;
    int cb0 = b * BCAP;
    int cb1 = gcur[b];                   // cb0 + bucket count
    for (int k = 0; k < 4; ++k) hist[tid * 4 + k] = 0;
    __syncthreads();
    for (int j = cb0 + tid; j < cb1; j += 256)
        atomicAdd(&hist[stage[j] & BMASK], 1);
    __syncthreads();
    int c0 = hist[tid*4], c1 = hist[tid*4+1], c2 = hist[tid*4+2], c3 = hist[tid*4+3];
    int s = c0 + c1 + c2 + c3;
    int x = s; tmp[tid] = x; __syncthreads();
    for (int o = 1; o < 256; o <<= 1) {
        int y = (tid >= o) ? tmp[tid - o] : 0;
        __syncthreads();
        x += y; tmp[tid] = x;
        __syncthreads();
    }
    int run = x - s;                 // exclusive prefix of this thread's 4 counters
    int nbase = b << BSHIFT;
    int counts[4] = {c0, c1, c2, c3};
    for (int k = 0; k < 4; ++k) {
        int v = tid * 4 + k;
        hist[v] = run;               // local cursor start
        int node = nbase + v;
        if (node < N_NODES) {
            off[node]  = cb0 + run;
            endv[node] = cb0 + run + counts[k];
            float di = rsqrtf((float)counts[k] + 1.0f);   // +1 self loop
            dinv[node] = di;
            float2 xv = x2[node];
            xs2[node] = make_float2(di * xv.x, di * xv.y);
        }
        run += counts[k];
    }
    __syncthreads();
    for (int j = cb0 + tid; j < cb1; j += 256) {
        int p = stage[j];
        int pos = atomicAdd(&hist[p & BMASK], 1);
        edges[cb0 + pos] = p >> BSHIFT;     // src
    }
    // zero-fill the gap [cb1, cb0+BCAP) — masked over-reads land on node 0
    for (int j = cb1 + tid; j < cb0 + BCAP; j += 256)
        edges[j] = 0;
}

static __device__ __forceinline__ float rdlf(float v, int l) {
    return __uint_as_float(__builtin_amdgcn_readlane(__float_as_uint(v), (unsigned)l));
}
static __device__ __forceinline__ int rdli(int v, int l) {
    return __builtin_amdgcn_readlane(v, (unsigned)l);
}
// fp16 row fragment (4 channels) -> fp32 accumulate
static __device__ __forceinline__ void acc4h(float4& a, uint2 r) {
    __half2 h01 = *reinterpret_cast<const __half2*>(&r.x);
    __half2 h23 = *reinterpret_cast<const __half2*>(&r.y);
    float2 f01 = __half22float2(h01);
    float2 f23 = __half22float2(h23);
    a.x += f01.x; a.y += f01.y; a.z += f23.x; a.w += f23.y;
}

// ---------- layer 1: chunked gather of prescaled x (value-prefetched) + W1 +
//            relu + fused W2, store fp16 prescaled rows ----------
__global__ __launch_bounds__(256, 4)
void k_l1(const int* __restrict__ edges, const int* __restrict__ off,
          const int* __restrict__ endv, const float* __restrict__ dinv,
          const float2* __restrict__ xs2,
          const float* __restrict__ W1, const float* __restrict__ b1,
          const float* __restrict__ W2, __half* __restrict__ Yout) {
    int lane = threadIdx.x & 63;
    int wid = blockIdx.x * 4 + (threadIdx.x >> 6);
    int n0 = wid * CPW;
    if (n0 >= N_NODES) return;
    float w1a = W1[lane], w1b = W1[64 + lane], bb = b1[lane];
    float4 wc[16];
#pragma unroll
    for (int t = 0; t < 16; ++t) {
        wc[t].x = W2[(4 * t + 0) * 64 + lane];
        wc[t].y = W2[(4 * t + 1) * 64 + lane];
        wc[t].z = W2[(4 * t + 2) * 64 + lane];
        wc[t].w = W2[(4 * t + 3) * 64 + lane];
    }
#pragma unroll
    for (int t = 0; t < 16; ++t) {
        asm volatile("" : "+v"(wc[t].x), "+v"(wc[t].y), "+v"(wc[t].z), "+v"(wc[t].w));
    }
    // chunk metadata in lanes 0..15
    int mo = 0, me = 0; float md = 0.0f; float sxx = 0.0f, sxy = 0.0f;
    if (lane < CPW) {
        int nn = n0 + lane;
        mo = off[nn]; me = endv[nn]; md = dinv[nn];
        float2 sv = xs2[nn];
        sxx = sv.x; sxy = sv.y;
    }
    int j0 = rdli(mo, 0);
    int deg0 = rdli(me, 0) - j0;
    int idx = j0 + lane;
    int ev = edges[idx];
    float pxv = 0.0f, pyv = 0.0f;                // prefetched gather values
    if (lane < deg0) {
        float2 v = xs2[ev];
        pxv = v.x; pyv = v.y;
    }
    for (int i = 0; i < CPW; ++i) {
        int n = n0 + i;
        float dn = rdlf(md, i);
        int deg = rdli(me, i) - j0;
        // prefetch next node's edge vector AND its gather values
        int evn = 0; int j0n = 0;
        float pxn = 0.0f, pyn = 0.0f;
        if (i < CPW - 1) {
            j0n = rdli(mo, i + 1);
            int degn = rdli(me, i + 1) - j0n;
            int idn = j0n + lane;
            evn = edges[idn];
            if (lane < degn) {
                float2 v = xs2[evn];
                pxn = v.x; pyn = v.y;
            }
        }
        float px = pxv, py = pyv;
        for (int jj = j0 + 64 + lane; jj < j0 + deg; jj += 64) {   // rare deg>64 tail
            float2 v = xs2[edges[jj]];
            px += v.x; py += v.y;
        }
#pragma unroll
        for (int o = 1; o < 64; o <<= 1) {
            px += __shfl_xor(px, o, 64);
            py += __shfl_xor(py, o, 64);
        }
        float gx = dn * (px + rdlf(sxx, i));
        float gy = dn * (py + rdlf(sxy, i));
        float h = gx * w1a + gy * w1b + bb;
        h = h > 0.0f ? h : 0.0f;
        float y0 = 0.0f, y1 = 0.0f, y2 = 0.0f, y3 = 0.0f;
#pragma unroll
        for (int t = 0; t < 16; ++t) {
            float4 w = wc[t];
            y0 = fmaf(rdlf(h, 4 * t + 0), w.x, y0);
            y1 = fmaf(rdlf(h, 4 * t + 1), w.y, y1);
            y2 = fmaf(rdlf(h, 4 * t + 2), w.z, y2);
            y3 = fmaf(rdlf(h, 4 * t + 3), w.w, y3);
        }
        Yout[n * 64 + lane] = __float2half(dn * ((y0 + y1) + (y2 + y3)));
        ev = evn; j0 = j0n; pxv = pxn; pyv = pyn;
    }
}

// ---------- layers 2/3: software-pipelined quad-row fp16 gather, 32-slot
//            prefetch (group-guarded, no waste): node i+1's first-32-edge
//            rows issue BEFORE node i's reduce+transform ----------
template<bool FINAL>
__global__ __launch_bounds__(256, 4)
void k_gl(const int* __restrict__ edges, const int* __restrict__ off,
          const int* __restrict__ endv, const float* __restrict__ dinv,
          const __half* __restrict__ Yin, const float* __restrict__ Wn,
          const float* __restrict__ bias, void* __restrict__ Yout) {
    const uint2* __restrict__ Yin2 = (const uint2*)Yin;   // 16 × 8B per 64-half row
    int lane = threadIdx.x & 63;
    int q = lane & 15, s = lane >> 4;          // sub-group: s = which row of a quad
    int wid = blockIdx.x * 4 + (threadIdx.x >> 6);
    int n0 = wid * CPW;
    if (n0 >= N_NODES) return;
    float bb = bias[lane];
    float4 wc[16];
    if (!FINAL) {
#pragma unroll
        for (int t = 0; t < 16; ++t) {
            wc[t].x = Wn[(4 * t + 0) * 64 + lane];
            wc[t].y = Wn[(4 * t + 1) * 64 + lane];
            wc[t].z = Wn[(4 * t + 2) * 64 + lane];
            wc[t].w = Wn[(4 * t + 3) * 64 + lane];
        }
#pragma unroll
        for (int t = 0; t < 16; ++t) {
            asm volatile("" : "+v"(wc[t].x), "+v"(wc[t].y), "+v"(wc[t].z), "+v"(wc[t].w));
        }
    }
    // chunk metadata in lanes 0..15
    int mo = 0, me = 0; float md = 0.0f;
    if (lane < CPW) {
        int nn = n0 + lane;
        mo = off[nn]; me = endv[nn]; md = dinv[nn];
    }
    int j0 = rdli(mo, 0);
    int j1 = rdli(me, 0);
    int m0 = j1 - j0; if (m0 > 64) m0 = 64;
    int idx = j0 + lane;
    int ev = edges[idx];                         // edge-index vector, node 0
    uint2 sraw = make_uint2(0u, 0u);
    if (s == 0) sraw = Yin2[(size_t)n0 * 16 + q];   // self row (prescaled fp16)
    // prologue: prefetch node 0's first-32-edge rows (group guards wave-uniform)
    uint2 r0 = make_uint2(0u, 0u), r1 = r0, r2 = r0, r3 = r0;
    uint2 r4 = r0, r5 = r0, r6 = r0, r7 = r0;
    {
        int i0 = __shfl(ev, 0 + s, 64);
        int i1 = __shfl(ev, 4 + s, 64);
        int i2 = __shfl(ev, 8 + s, 64);
        int i3 = __shfl(ev, 12 + s, 64);
        int i4 = __shfl(ev, 16 + s, 64);
        int i5 = __shfl(ev, 20 + s, 64);
        int i6 = __shfl(ev, 24 + s, 64);
        int i7 = __shfl(ev, 28 + s, 64);
        if (m0 > 0)  r0 = Yin2[(size_t)i0 * 16 + q];
        if (m0 > 4)  r1 = Yin2[(size_t)i1 * 16 + q];
        if (m0 > 8)  r2 = Yin2[(size_t)i2 * 16 + q];
        if (m0 > 12) r3 = Yin2[(size_t)i3 * 16 + q];
        if (m0 > 16) r4 = Yin2[(size_t)i4 * 16 + q];
        if (m0 > 20) r5 = Yin2[(size_t)i5 * 16 + q];
        if (m0 > 24) r6 = Yin2[(size_t)i6 * 16 + q];
        if (m0 > 28) r7 = Yin2[(size_t)i7 * 16 + q];
    }
    for (int i = 0; i < CPW; ++i) {
        int n = n0 + i;
        float dn = rdlf(md, i);
        int deg = rdli(me, i) - j0;
        int m = m0;
        // next node's metadata + edge vector + self row (issue early)
        int evn = 0; int j0n = 0; int mn = 0;
        uint2 srn = make_uint2(0u, 0u);
        if (i < CPW - 1) {
            j0n = rdli(mo, i + 1);
            int j1n = rdli(me, i + 1);
            mn = j1n - j0n; if (mn > 64) mn = 64;
            int idn = j0n + lane;
            evn = edges[idn];
            if (s == 0) srn = Yin2[(size_t)(n + 1) * 16 + q];
        }
        // ---- accumulate prefetched first-32 rows (per-lane slot mask) ----
        float4 acc = make_float4(0.f, 0.f, 0.f, 0.f);
        if (s == 0) acc4h(acc, sraw);
        if (0 + s < m)  acc4h(acc, r0);
        if (4 + s < m)  acc4h(acc, r1);
        if (8 + s < m)  acc4h(acc, r2);
        if (12 + s < m) acc4h(acc, r3);
        if (16 + s < m) acc4h(acc, r4);
        if (20 + s < m) acc4h(acc, r5);
        if (24 + s < m) acc4h(acc, r6);
        if (28 + s < m) acc4h(acc, r7);
        // ---- remainder 32..m in-line (uniform group bound, per-lane mask) ----
        for (int t = 8; 4 * t < m; ++t) {
            int sl = 4 * t + s;
            int ii = __shfl(ev, sl, 64);
            uint2 rr = Yin2[(size_t)ii * 16 + q];
            if (sl < m) acc4h(acc, rr);
        }
        // ---- rare deg>64 tail (sub 0 only) ----
        for (int jj = 64; jj < deg; ++jj) {
            int sidx = edges[j0 + jj];
            if (s == 0) {
                uint2 rr = Yin2[(size_t)sidx * 16 + q];
                acc4h(acc, rr);
            }
        }
        // ---- PREFETCH next node's rows: results not used until next iter,
        //      so the vmcnt wait lands after the transform below ----
        if (i < CPW - 1) {
            int i0 = __shfl(evn, 0 + s, 64);
            int i1 = __shfl(evn, 4 + s, 64);
            int i2 = __shfl(evn, 8 + s, 64);
            int i3 = __shfl(evn, 12 + s, 64);
            int i4 = __shfl(evn, 16 + s, 64);
            int i5 = __shfl(evn, 20 + s, 64);
            int i6 = __shfl(evn, 24 + s, 64);
            int i7 = __shfl(evn, 28 + s, 64);
            r0 = make_uint2(0u, 0u); r1 = r0; r2 = r0; r3 = r0;
            r4 = r0; r5 = r0; r6 = r0; r7 = r0;
            if (mn > 0)  r0 = Yin2[(size_t)i0 * 16 + q];
            if (mn > 4)  r1 = Yin2[(size_t)i1 * 16 + q];
            if (mn > 8)  r2 = Yin2[(size_t)i2 * 16 + q];
            if (mn > 12) r3 = Yin2[(size_t)i3 * 16 + q];
            if (mn > 16) r4 = Yin2[(size_t)i4 * 16 + q];
            if (mn > 20) r5 = Yin2[(size_t)i5 * 16 + q];
            if (mn > 24) r6 = Yin2[(size_t)i6 * 16 + q];
            if (mn > 28) r7 = Yin2[(size_t)i7 * 16 + q];
        }
        // ---- combine the 4 sub-groups (long VALU stretch covers prefetch) ----
        acc.x += __shfl_xor(acc.x, 16, 64); acc.x += __shfl_xor(acc.x, 32, 64);
        acc.y += __shfl_xor(acc.y, 16, 64); acc.y += __shfl_xor(acc.y, 32, 64);
        acc.z += __shfl_xor(acc.z, 16, 64); acc.z += __shfl_xor(acc.z, 32, 64);
        acc.w += __shfl_xor(acc.w, 16, 64); acc.w += __shfl_xor(acc.w, 32, 64);
        // redistribute: channel-per-lane layout
        int srcl = lane >> 2;
        float c0 = __shfl(acc.x, srcl, 64);
        float c1 = __shfl(acc.y, srcl, 64);
        float c2 = __shfl(acc.z, srcl, 64);
        float c3 = __shfl(acc.w, srcl, 64);
        float lo = (lane & 1) ? c1 : c0;
        float hi = (lane & 1) ? c3 : c2;
        float sumc = (lane & 2) ? hi : lo;
        float h = dn * sumc + bb;
        h = h > 0.0f ? h : 0.0f;
        if (FINAL) {
            ((__half*)Yout)[n * 64 + lane] = __float2half(h);
        } else {
            float y0 = 0.0f, y1 = 0.0f, y2 = 0.0f, y3 = 0.0f;
#pragma unroll
            for (int t2 = 0; t2 < 16; ++t2) {
                float4 w = wc[t2];
                y0 = fmaf(rdlf(h, 4 * t2 + 0), w.x, y0);
                y1 = fmaf(rdlf(h, 4 * t2 + 1), w.y, y1);
                y2 = fmaf(rdlf(h, 4 * t2 + 2), w.z, y2);
                y3 = fmaf(rdlf(h, 4 * t2 + 3), w.w, y3);
            }
            ((__half*)Yout)[n * 64 + lane] = __float2half(dn * ((y0 + y1) + (y2 + y3)));
        }
        ev = evn; sraw = srn; j0 = j0n; m0 = mn;
    }
}

// ---------- segmented mean-pool accumulation (batch is sorted), fp16 input ----------
#define PCHUNK 64
__global__ void k_pool(const __half* __restrict__ A, const int* __restrict__ batch,
                       float* __restrict__ sums, float* __restrict__ cnts) {
    int c = threadIdx.x;
    int n0 = blockIdx.x * PCHUNK;
    int n1 = n0 + PCHUNK; if (n1 > N_NODES) n1 = N_NODES;
    int gcur = batch[n0];
    float acc = 0.0f;
    int cnt = 0;
    for (int n = n0; n < n1; ++n) {
        int g = batch[n];
        if (g != gcur) {
            atomicAdd(&sums[gcur * 64 + c], acc);
            if (c == 0) atomicAdd(&cnts[gcur], (float)cnt);
            acc = 0.0f; cnt = 0; gcur = g;
        }
        acc += __half2float(A[n * 64 + c]);
        ++cnt;
    }
    atomicAdd(&sums[gcur * 64 + c], acc);
    if (c == 0) atomicAdd(&cnts[gcur], (float)cnt);
}

// ---------- MLP head ----------
__global__ void k_head(const float* __restrict__ sums, const float* __restrict__ cnts,
                       const float* __restrict__ Wf1, const float* __restrict__ bf1,
                       const float* __restrict__ Wf2, const float* __restrict__ bf2,
                       float* __restrict__ out) {
    __shared__ float p[64];
    __shared__ float h[64];
    int g = blockIdx.x;
    int c = threadIdx.x;
    float cnt = cnts[g];
    cnt = cnt > 1.0f ? cnt : 1.0f;
    p[c] = sums[g * 64 + c] / cnt;
    __syncthreads();
    float s = bf1[c];
#pragma unroll
    for (int k = 0; k < 64; ++k) s += p[k] * Wf1[k * 64 + c];
    h[c] = s > 0.0f ? s : 0.0f;
    __syncthreads();
    if (c < N_CLASSES) {
        float o = bf2[c];
#pragma unroll
        for (int k = 0; k < 64; ++k) o += h[k] * Wf2[k * N_CLASSES + c];
        out[g * N_CLASSES + c] = o;
    }
}

extern "C" void kernel_launch(void* const* d_in, const int* in_sizes, int n_in,
                              void* d_out, int out_size, void* d_ws, size_t ws_size,
                              hipStream_t stream) {
    const float* x   = (const float*)d_in[0];
    const int*   ei  = (const int*)d_in[1];
    const int*   bat = (const int*)d_in[2];
    const float* W1  = (const float*)d_in[3];
    const float* b1  = (const float*)d_in[4];
    const float* W2  = (const float*)d_in[5];
    const float* b2  = (const float*)d_in[6];
    const float* W3  = (const float*)d_in[7];
    const float* b3  = (const float*)d_in[8];
    const float* Wf1 = (const float*)d_in[9];
    const float* bf1 = (const float*)d_in[10];
    const float* Wf2 = (const float*)d_in[11];
    const float* bf2 = (const float*)d_in[12];
    float* out = (float*)d_out;

    const int* src = ei;
    const int* dst = ei + N_EDGES;

    char* p = (char*)d_ws;
    __half* Ah   = (__half*)p;  p += (size_t)N_NODES * 64 * 2;   // fp16 final acts
    __half* Ph   = (__half*)p;  p += (size_t)N_NODES * 64 * 2;   // fp16 prescaled (post-L1)
    __half* Qh   = (__half*)p;  p += (size_t)N_NODES * 64 * 2;   // fp16 prescaled (post-L2)
    int*   stage = (int*)p;     p += (size_t)NBUCK * BCAP * 4;   // fixed-slot buckets
    int*   edges = (int*)p;     p += (size_t)NBUCK * BCAP * 4;   // gapped CSR payload
    int*   off   = (int*)p;     p += (size_t)N_NODES * 4;
    int*   endv  = (int*)p;     p += (size_t)N_NODES * 4;
    float* dinv  = (float*)p;   p += (size_t)N_NODES * 4;
    float* xs2   = (float*)p;   p += (size_t)N_NODES * 2 * 4;
    int*   gcur  = (int*)p;     p += (size_t)256 * 4;
    float* sums  = (float*)p;   p += (size_t)N_GRAPHS * 64 * 4;
    float* cnts  = (float*)p;   p += (size_t)N_GRAPHS * 4;

    hipMemsetAsync(sums, 0, (size_t)(N_GRAPHS * 64 + N_GRAPHS) * 4, stream);

    const int BT = 256;
    int gPart = (N_EDGES + PT_EDGES - 1) / PT_EDGES;             // 391

    // ---- CSR build (fixed-capacity buckets: no histogram/scan passes) ----
    k_init<<<1, 256, 0, stream>>>(gcur);
    k_part<<<gPart, BT, 0, stream>>>(src, dst, gcur, stage);
    k_sort<<<NBUCK, 256, 0, stream>>>(stage, gcur, edges, off, endv, dinv,
                                      (const float2*)x, (float2*)xs2);

    // ---- layer 1 (pipelined gather x, W1, relu, fused W2 + prescale, fp16 out) ----
    k_l1<<<GLAYER, BT, 0, stream>>>(edges, off, endv, dinv, (const float2*)xs2,
                                    W1, b1, W2, Ph);

    // ---- layer 2 (pipelined fp16 quad gather + b2/relu + fused W3, fp16 out) ----
    k_gl<false><<<GLAYER, BT, 0, stream>>>(edges, off, endv, dinv, Ph, W3, b2, Qh);

    // ---- layer 3 (pipelined fp16 quad gather + b3/relu, fp16 final acts) ----
    k_gl<true><<<GLAYER, BT, 0, stream>>>(edges, off, endv, dinv, Qh, nullptr, b3, Ah);

    // ---- pool + head ----
    k_pool<<<(N_NODES + PCHUNK - 1) / PCHUNK, 64, 0, stream>>>(Ah, bat, sums, cnts);
    k_head<<<N_GRAPHS, 64, 0, stream>>>(sums, cnts, Wf1, bf1, Wf2, bf2, out);
}

// Round 19
// 406.000 us; speedup vs baseline: 1.4502x; 1.0792x over previous
//
#include <hip/hip_runtime.h>
#include <hip/hip_fp16.h>

#define N_NODES  200000
#define N_EDGES  3200000
#define HIDDEN   64
#define N_GRAPHS 4096
#define N_CLASSES 7
#define NBUCK    196          // ceil(N_NODES / 1024)
#define BSHIFT   10
#define BMASK    1023
#define BCAP     18432        // fixed bucket capacity (E=16384, sigma~128, 16-sigma margin)
#define CPW      16           // nodes (chunk) per wave
#define NCHUNK   (N_NODES / CPW)          // 12500
#define GLAYER   (NCHUNK / 4)             // 3125 blocks of 4 waves

// ---------- init per-bucket cursors to fixed slot bases ----------
__global__ void k_init(int* __restrict__ gcur) {
    int tid = threadIdx.x;
    if (tid < NBUCK) gcur[tid] = tid * BCAP;
}

// ---------- coarse partition, LDS-staged: block-local counting sort into LDS,
//            then bucket-contiguous (coalesced) global writes into fixed slots ----------
#define PT_EPT 32
#define PT_EDGES (256 * PT_EPT)           // 8192 edges per block
__global__ void k_part(const int* __restrict__ src, const int* __restrict__ dst,
                       int* __restrict__ gcur, int* __restrict__ stage) {
    __shared__ int lh[NBUCK];
    __shared__ int lofs[NBUCK];
    __shared__ int lbase[NBUCK];
    __shared__ int lcur[NBUCK];
    __shared__ int tmp[256];
    __shared__ int buf[PT_EDGES];         // 32 KB staged payloads
    __shared__ unsigned char bid[PT_EDGES];   // bucket id per staged slot
    int tid = threadIdx.x;
    for (int i = tid; i < NBUCK; i += 256) { lh[i] = 0; lcur[i] = 0; }
    __syncthreads();
    int base = blockIdx.x * PT_EDGES + tid;
    for (int k = 0; k < PT_EPT; ++k) {
        int e = base + k * 256;
        if (e < N_EDGES) atomicAdd(&lh[dst[e] >> BSHIFT], 1);
    }
    __syncthreads();
    // block scan of 196 bucket counts -> local offsets; reserve global ranges
    int v = (tid < NBUCK) ? lh[tid] : 0;
    int x = v; tmp[tid] = x; __syncthreads();
    for (int o = 1; o < 256; o <<= 1) {
        int y = (tid >= o) ? tmp[tid - o] : 0;
        __syncthreads();
        x += y; tmp[tid] = x;
        __syncthreads();
    }
    if (tid < NBUCK) {
        lofs[tid] = x - v;
        if (v > 0) lbase[tid] = atomicAdd(&gcur[tid], v);
    }
    __syncthreads();
    // scatter into LDS (cheap) instead of global
    for (int k = 0; k < PT_EPT; ++k) {
        int e = base + k * 256;
        if (e < N_EDGES) {
            int d = dst[e], b = d >> BSHIFT;
            int lp = lofs[b] + atomicAdd(&lcur[b], 1);
            buf[lp] = (src[e] << BSHIFT) | (d & BMASK);
            bid[lp] = (unsigned char)b;
        }
    }
    __syncthreads();
    // bucket-contiguous global writes (runs of ~42 edges -> coalesced)
    int nval = N_EDGES - blockIdx.x * PT_EDGES;
    if (nval > PT_EDGES) nval = PT_EDGES;
    for (int l = tid; l < nval; l += 256) {
        int b = bid[l];
        stage[lbase[b] + (l - lofs[b])] = buf[l];
    }
}

// ---------- per-bucket exact sort + CSR metadata; also prescale x by dinv.
//            ZERO-FILLS the bucket gap so downstream over-reads see valid
//            node index 0 (masked out of sums, but in-bounds). ----------
__global__ void k_sort(const int* __restrict__ stage, const int* __restrict__ gcur,
                       int* __restrict__ edges, int* __restrict__ off,
                       int* __restrict__ endv, float* __restrict__ dinv,
                       const float2* __restrict__ x2, float2* __restrict__ xs2) {
    __shared__ int hist[1024];
    __shared__ int tmp[256];
    int b = blockIdx.x, tid = threadIdx.x;
    int cb0 = b * BCAP;
    int cb1 = gcur[b];                   // cb0 + bucket count
    for (int k = 0; k < 4; ++k) hist[tid * 4 + k] = 0;
    __syncthreads();
    for (int j = cb0 + tid; j < cb1; j += 256)
        atomicAdd(&hist[stage[j] & BMASK], 1);
    __syncthreads();
    int c0 = hist[tid*4], c1 = hist[tid*4+1], c2 = hist[tid*4+2], c3 = hist[tid*4+3];
    int s = c0 + c1 + c2 + c3;
    int x = s; tmp[tid] = x; __syncthreads();
    for (int o = 1; o < 256; o <<= 1) {
        int y = (tid >= o) ? tmp[tid - o] : 0;
        __syncthreads();
        x += y; tmp[tid] = x;
        __syncthreads();
    }
    int run = x - s;                 // exclusive prefix of this thread's 4 counters
    int nbase = b << BSHIFT;
    int counts[4] = {c0, c1, c2, c3};
    for (int k = 0; k < 4; ++k) {
        int v = tid * 4 + k;
        hist[v] = run;               // local cursor start
        int node = nbase + v;
        if (node < N_NODES) {
            off[node]  = cb0 + run;
            endv[node] = cb0 + run + counts[k];
            float di = rsqrtf((float)counts[k] + 1.0f);   // +1 self loop
            dinv[node] = di;
            float2 xv = x2[node];
            xs2[node] = make_float2(di * xv.x, di * xv.y);
        }
        run += counts[k];
    }
    __syncthreads();
    for (int j = cb0 + tid; j < cb1; j += 256) {
        int p = stage[j];
        int pos = atomicAdd(&hist[p & BMASK], 1);
        edges[cb0 + pos] = p >> BSHIFT;     // src
    }
    // zero-fill the gap [cb1, cb0+BCAP) — masked over-reads land on node 0
    for (int j = cb1 + tid; j < cb0 + BCAP; j += 256)
        edges[j] = 0;
}

static __device__ __forceinline__ float rdlf(float v, int l) {
    return __uint_as_float(__builtin_amdgcn_readlane(__float_as_uint(v), (unsigned)l));
}
static __device__ __forceinline__ int rdli(int v, int l) {
    return __builtin_amdgcn_readlane(v, (unsigned)l);
}
// fp16 row fragment (4 channels) -> fp32 accumulate
static __device__ __forceinline__ void acc4h(float4& a, uint2 r) {
    __half2 h01 = *reinterpret_cast<const __half2*>(&r.x);
    __half2 h23 = *reinterpret_cast<const __half2*>(&r.y);
    float2 f01 = __half22float2(h01);
    float2 f23 = __half22float2(h23);
    a.x += f01.x; a.y += f01.y; a.z += f23.x; a.w += f23.y;
}

// ---------- layer 1: chunked gather of prescaled x (value-prefetched) + W1 +
//            relu + fused W2, store fp16 prescaled rows ----------
__global__ __launch_bounds__(256, 4)
void k_l1(const int* __restrict__ edges, const int* __restrict__ off,
          const int* __restrict__ endv, const float* __restrict__ dinv,
          const float2* __restrict__ xs2,
          const float* __restrict__ W1, const float* __restrict__ b1,
          const float* __restrict__ W2, __half* __restrict__ Yout) {
    int lane = threadIdx.x & 63;
    int wid = blockIdx.x * 4 + (threadIdx.x >> 6);
    int n0 = wid * CPW;
    if (n0 >= N_NODES) return;
    float w1a = W1[lane], w1b = W1[64 + lane], bb = b1[lane];
    float4 wc[16];
#pragma unroll
    for (int t = 0; t < 16; ++t) {
        wc[t].x = W2[(4 * t + 0) * 64 + lane];
        wc[t].y = W2[(4 * t + 1) * 64 + lane];
        wc[t].z = W2[(4 * t + 2) * 64 + lane];
        wc[t].w = W2[(4 * t + 3) * 64 + lane];
    }
#pragma unroll
    for (int t = 0; t < 16; ++t) {
        asm volatile("" : "+v"(wc[t].x), "+v"(wc[t].y), "+v"(wc[t].z), "+v"(wc[t].w));
    }
    // chunk metadata in lanes 0..15
    int mo = 0, me = 0; float md = 0.0f; float sxx = 0.0f, sxy = 0.0f;
    if (lane < CPW) {
        int nn = n0 + lane;
        mo = off[nn]; me = endv[nn]; md = dinv[nn];
        float2 sv = xs2[nn];
        sxx = sv.x; sxy = sv.y;
    }
    int j0 = rdli(mo, 0);
    int deg0 = rdli(me, 0) - j0;
    int idx = j0 + lane;
    int ev = edges[idx];
    float pxv = 0.0f, pyv = 0.0f;                // prefetched gather values
    if (lane < deg0) {
        float2 v = xs2[ev];
        pxv = v.x; pyv = v.y;
    }
    for (int i = 0; i < CPW; ++i) {
        int n = n0 + i;
        float dn = rdlf(md, i);
        int deg = rdli(me, i) - j0;
        // prefetch next node's edge vector AND its gather values
        int evn = 0; int j0n = 0;
        float pxn = 0.0f, pyn = 0.0f;
        if (i < CPW - 1) {
            j0n = rdli(mo, i + 1);
            int degn = rdli(me, i + 1) - j0n;
            int idn = j0n + lane;
            evn = edges[idn];
            if (lane < degn) {
                float2 v = xs2[evn];
                pxn = v.x; pyn = v.y;
            }
        }
        float px = pxv, py = pyv;
        for (int jj = j0 + 64 + lane; jj < j0 + deg; jj += 64) {   // rare deg>64 tail
            float2 v = xs2[edges[jj]];
            px += v.x; py += v.y;
        }
#pragma unroll
        for (int o = 1; o < 64; o <<= 1) {
            px += __shfl_xor(px, o, 64);
            py += __shfl_xor(py, o, 64);
        }
        float gx = dn * (px + rdlf(sxx, i));
        float gy = dn * (py + rdlf(sxy, i));
        float h = gx * w1a + gy * w1b + bb;
        h = h > 0.0f ? h : 0.0f;
        float y0 = 0.0f, y1 = 0.0f, y2 = 0.0f, y3 = 0.0f;
#pragma unroll
        for (int t = 0; t < 16; ++t) {
            float4 w = wc[t];
            y0 = fmaf(rdlf(h, 4 * t + 0), w.x, y0);
            y1 = fmaf(rdlf(h, 4 * t + 1), w.y, y1);
            y2 = fmaf(rdlf(h, 4 * t + 2), w.z, y2);
            y3 = fmaf(rdlf(h, 4 * t + 3), w.w, y3);
        }
        Yout[n * 64 + lane] = __float2half(dn * ((y0 + y1) + (y2 + y3)));
        ev = evn; j0 = j0n; pxv = pxn; pyv = pyn;
    }
}

// ---------- layers 2/3: software-pipelined quad-row fp16 gather, 32-slot
//            prefetch. FINAL fuses the mean-pool accumulation (batch sorted):
//            run-accumulate per graph, atomic flush at graph boundaries. ----------
template<bool FINAL>
__global__ __launch_bounds__(256, 4)
void k_gl(const int* __restrict__ edges, const int* __restrict__ off,
          const int* __restrict__ endv, const float* __restrict__ dinv,
          const __half* __restrict__ Yin, const float* __restrict__ Wn,
          const float* __restrict__ bias, __half* __restrict__ Yout,
          const int* __restrict__ bat, float* __restrict__ sums,
          float* __restrict__ cnts) {
    const uint2* __restrict__ Yin2 = (const uint2*)Yin;   // 16 × 8B per 64-half row
    int lane = threadIdx.x & 63;
    int q = lane & 15, s = lane >> 4;          // sub-group: s = which row of a quad
    int wid = blockIdx.x * 4 + (threadIdx.x >> 6);
    int n0 = wid * CPW;
    if (n0 >= N_NODES) return;
    float bb = bias[lane];
    float4 wc[16];
    if (!FINAL) {
#pragma unroll
        for (int t = 0; t < 16; ++t) {
            wc[t].x = Wn[(4 * t + 0) * 64 + lane];
            wc[t].y = Wn[(4 * t + 1) * 64 + lane];
            wc[t].z = Wn[(4 * t + 2) * 64 + lane];
            wc[t].w = Wn[(4 * t + 3) * 64 + lane];
        }
#pragma unroll
        for (int t = 0; t < 16; ++t) {
            asm volatile("" : "+v"(wc[t].x), "+v"(wc[t].y), "+v"(wc[t].z), "+v"(wc[t].w));
        }
    }
    // chunk metadata in lanes 0..15 (FINAL also loads batch ids)
    int mo = 0, me = 0; float md = 0.0f; int bt = 0;
    if (lane < CPW) {
        int nn = n0 + lane;
        mo = off[nn]; me = endv[nn]; md = dinv[nn];
        if (FINAL) bt = bat[nn];
    }
    int j0 = rdli(mo, 0);
    int j1 = rdli(me, 0);
    int m0 = j1 - j0; if (m0 > 64) m0 = 64;
    int idx = j0 + lane;
    int ev = edges[idx];                         // edge-index vector, node 0
    uint2 sraw = make_uint2(0u, 0u);
    if (s == 0) sraw = Yin2[(size_t)n0 * 16 + q];   // self row (prescaled fp16)
    // prologue: prefetch node 0's first-32-edge rows (group guards wave-uniform)
    uint2 r0 = make_uint2(0u, 0u), r1 = r0, r2 = r0, r3 = r0;
    uint2 r4 = r0, r5 = r0, r6 = r0, r7 = r0;
    {
        int i0 = __shfl(ev, 0 + s, 64);
        int i1 = __shfl(ev, 4 + s, 64);
        int i2 = __shfl(ev, 8 + s, 64);
        int i3 = __shfl(ev, 12 + s, 64);
        int i4 = __shfl(ev, 16 + s, 64);
        int i5 = __shfl(ev, 20 + s, 64);
        int i6 = __shfl(ev, 24 + s, 64);
        int i7 = __shfl(ev, 28 + s, 64);
        if (m0 > 0)  r0 = Yin2[(size_t)i0 * 16 + q];
        if (m0 > 4)  r1 = Yin2[(size_t)i1 * 16 + q];
        if (m0 > 8)  r2 = Yin2[(size_t)i2 * 16 + q];
        if (m0 > 12) r3 = Yin2[(size_t)i3 * 16 + q];
        if (m0 > 16) r4 = Yin2[(size_t)i4 * 16 + q];
        if (m0 > 20) r5 = Yin2[(size_t)i5 * 16 + q];
        if (m0 > 24) r6 = Yin2[(size_t)i6 * 16 + q];
        if (m0 > 28) r7 = Yin2[(size_t)i7 * 16 + q];
    }
    // fused-pool running state (FINAL only)
    float accp = 0.0f; int cntp = 0; int gprev = rdli(bt, 0);
    for (int i = 0; i < CPW; ++i) {
        int n = n0 + i;
        float dn = rdlf(md, i);
        int deg = rdli(me, i) - j0;
        int m = m0;
        // next node's metadata + edge vector + self row (issue early)
        int evn = 0; int j0n = 0; int mn = 0;
        uint2 srn = make_uint2(0u, 0u);
        if (i < CPW - 1) {
            j0n = rdli(mo, i + 1);
            int j1n = rdli(me, i + 1);
            mn = j1n - j0n; if (mn > 64) mn = 64;
            int idn = j0n + lane;
            evn = edges[idn];
            if (s == 0) srn = Yin2[(size_t)(n + 1) * 16 + q];
        }
        // ---- accumulate prefetched first-32 rows (per-lane slot mask) ----
        float4 acc = make_float4(0.f, 0.f, 0.f, 0.f);
        if (s == 0) acc4h(acc, sraw);
        if (0 + s < m)  acc4h(acc, r0);
        if (4 + s < m)  acc4h(acc, r1);
        if (8 + s < m)  acc4h(acc, r2);
        if (12 + s < m) acc4h(acc, r3);
        if (16 + s < m) acc4h(acc, r4);
        if (20 + s < m) acc4h(acc, r5);
        if (24 + s < m) acc4h(acc, r6);
        if (28 + s < m) acc4h(acc, r7);
        // ---- remainder 32..m in-line (uniform group bound, per-lane mask) ----
        for (int t = 8; 4 * t < m; ++t) {
            int sl = 4 * t + s;
            int ii = __shfl(ev, sl, 64);
            uint2 rr = Yin2[(size_t)ii * 16 + q];
            if (sl < m) acc4h(acc, rr);
        }
        // ---- rare deg>64 tail (sub 0 only) ----
        for (int jj = 64; jj < deg; ++jj) {
            int sidx = edges[j0 + jj];
            if (s == 0) {
                uint2 rr = Yin2[(size_t)sidx * 16 + q];
                acc4h(acc, rr);
            }
        }
        // ---- PREFETCH next node's rows: results not used until next iter,
        //      so the vmcnt wait lands after the transform below ----
        if (i < CPW - 1) {
            int i0 = __shfl(evn, 0 + s, 64);
            int i1 = __shfl(evn, 4 + s, 64);
            int i2 = __shfl(evn, 8 + s, 64);
            int i3 = __shfl(evn, 12 + s, 64);
            int i4 = __shfl(evn, 16 + s, 64);
            int i5 = __shfl(evn, 20 + s, 64);
            int i6 = __shfl(evn, 24 + s, 64);
            int i7 = __shfl(evn, 28 + s, 64);
            r0 = make_uint2(0u, 0u); r1 = r0; r2 = r0; r3 = r0;
            r4 = r0; r5 = r0; r6 = r0; r7 = r0;
            if (mn > 0)  r0 = Yin2[(size_t)i0 * 16 + q];
            if (mn > 4)  r1 = Yin2[(size_t)i1 * 16 + q];
            if (mn > 8)  r2 = Yin2[(size_t)i2 * 16 + q];
            if (mn > 12) r3 = Yin2[(size_t)i3 * 16 + q];
            if (mn > 16) r4 = Yin2[(size_t)i4 * 16 + q];
            if (mn > 20) r5 = Yin2[(size_t)i5 * 16 + q];
            if (mn > 24) r6 = Yin2[(size_t)i6 * 16 + q];
            if (mn > 28) r7 = Yin2[(size_t)i7 * 16 + q];
        }
        // ---- combine the 4 sub-groups (long VALU stretch covers prefetch) ----
        acc.x += __shfl_xor(acc.x, 16, 64); acc.x += __shfl_xor(acc.x, 32, 64);
        acc.y += __shfl_xor(acc.y, 16, 64); acc.y += __shfl_xor(acc.y, 32, 64);
        acc.z += __shfl_xor(acc.z, 16, 64); acc.z += __shfl_xor(acc.z, 32, 64);
        acc.w += __shfl_xor(acc.w, 16, 64); acc.w += __shfl_xor(acc.w, 32, 64);
        // redistribute: channel-per-lane layout
        int srcl = lane >> 2;
        float c0 = __shfl(acc.x, srcl, 64);
        float c1 = __shfl(acc.y, srcl, 64);
        float c2 = __shfl(acc.z, srcl, 64);
        float c3 = __shfl(acc.w, srcl, 64);
        float lo = (lane & 1) ? c1 : c0;
        float hi = (lane & 1) ? c3 : c2;
        float sumc = (lane & 2) ? hi : lo;
        float h = dn * sumc + bb;
        h = h > 0.0f ? h : 0.0f;
        if (FINAL) {
            int g = rdli(bt, i);
            if (g != gprev) {                    // flush previous graph's run
                atomicAdd(&sums[(size_t)gprev * 64 + lane], accp);
                if (lane == 0) atomicAdd(&cnts[gprev], (float)cntp);
                accp = 0.0f; cntp = 0; gprev = g;
            }
            accp += h; ++cntp;
        } else {
            float y0 = 0.0f, y1 = 0.0f, y2 = 0.0f, y3 = 0.0f;
#pragma unroll
            for (int t2 = 0; t2 < 16; ++t2) {
                float4 w = wc[t2];
                y0 = fmaf(rdlf(h, 4 * t2 + 0), w.x, y0);
                y1 = fmaf(rdlf(h, 4 * t2 + 1), w.y, y1);
                y2 = fmaf(rdlf(h, 4 * t2 + 2), w.z, y2);
                y3 = fmaf(rdlf(h, 4 * t2 + 3), w.w, y3);
            }
            Yout[n * 64 + lane] = __float2half(dn * ((y0 + y1) + (y2 + y3)));
        }
        ev = evn; sraw = srn; j0 = j0n; m0 = mn;
    }
    if (FINAL) {                                 // flush the last run
        atomicAdd(&sums[(size_t)gprev * 64 + lane], accp);
        if (lane == 0) atomicAdd(&cnts[gprev], (float)cntp);
    }
}

// ---------- MLP head ----------
__global__ void k_head(const float* __restrict__ sums, const float* __restrict__ cnts,
                       const float* __restrict__ Wf1, const float* __restrict__ bf1,
                       const float* __restrict__ Wf2, const float* __restrict__ bf2,
                       float* __restrict__ out) {
    __shared__ float p[64];
    __shared__ float h[64];
    int g = blockIdx.x;
    int c = threadIdx.x;
    float cnt = cnts[g];
    cnt = cnt > 1.0f ? cnt : 1.0f;
    p[c] = sums[g * 64 + c] / cnt;
    __syncthreads();
    float s = bf1[c];
#pragma unroll
    for (int k = 0; k < 64; ++k) s += p[k] * Wf1[k * 64 + c];
    h[c] = s > 0.0f ? s : 0.0f;
    __syncthreads();
    if (c < N_CLASSES) {
        float o = bf2[c];
#pragma unroll
        for (int k = 0; k < 64; ++k) o += h[k] * Wf2[k * N_CLASSES + c];
        out[g * N_CLASSES + c] = o;
    }
}

extern "C" void kernel_launch(void* const* d_in, const int* in_sizes, int n_in,
                              void* d_out, int out_size, void* d_ws, size_t ws_size,
                              hipStream_t stream) {
    const float* x   = (const float*)d_in[0];
    const int*   ei  = (const int*)d_in[1];
    const int*   bat = (const int*)d_in[2];
    const float* W1  = (const float*)d_in[3];
    const float* b1  = (const float*)d_in[4];
    const float* W2  = (const float*)d_in[5];
    const float* b2  = (const float*)d_in[6];
    const float* W3  = (const float*)d_in[7];
    const float* b3  = (const float*)d_in[8];
    const float* Wf1 = (const float*)d_in[9];
    const float* bf1 = (const float*)d_in[10];
    const float* Wf2 = (const float*)d_in[11];
    const float* bf2 = (const float*)d_in[12];
    float* out = (float*)d_out;

    const int* src = ei;
    const int* dst = ei + N_EDGES;

    char* p = (char*)d_ws;
    __half* Ph   = (__half*)p;  p += (size_t)N_NODES * 64 * 2;   // fp16 prescaled (post-L1)
    __half* Qh   = (__half*)p;  p += (size_t)N_NODES * 64 * 2;   // fp16 prescaled (post-L2)
    int*   stage = (int*)p;     p += (size_t)NBUCK * BCAP * 4;   // fixed-slot buckets
    int*   edges = (int*)p;     p += (size_t)NBUCK * BCAP * 4;   // gapped CSR payload
    int*   off   = (int*)p;     p += (size_t)N_NODES * 4;
    int*   endv  = (int*)p;     p += (size_t)N_NODES * 4;
    float* dinv  = (float*)p;   p += (size_t)N_NODES * 4;
    float* xs2   = (float*)p;   p += (size_t)N_NODES * 2 * 4;
    int*   gcur  = (int*)p;     p += (size_t)256 * 4;
    float* sums  = (float*)p;   p += (size_t)N_GRAPHS * 64 * 4;
    float* cnts  = (float*)p;   p += (size_t)N_GRAPHS * 4;

    hipMemsetAsync(sums, 0, (size_t)(N_GRAPHS * 64 + N_GRAPHS) * 4, stream);

    const int BT = 256;
    int gPart = (N_EDGES + PT_EDGES - 1) / PT_EDGES;             // 391

    // ---- CSR build (fixed-capacity buckets: no histogram/scan passes) ----
    k_init<<<1, 256, 0, stream>>>(gcur);
    k_part<<<gPart, BT, 0, stream>>>(src, dst, gcur, stage);
    k_sort<<<NBUCK, 256, 0, stream>>>(stage, gcur, edges, off, endv, dinv,
                                      (const float2*)x, (float2*)xs2);

    // ---- layer 1 (pipelined gather x, W1, relu, fused W2 + prescale, fp16 out) ----
    k_l1<<<GLAYER, BT, 0, stream>>>(edges, off, endv, dinv, (const float2*)xs2,
                                    W1, b1, W2, Ph);

    // ---- layer 2 (pipelined fp16 quad gather + b2/relu + fused W3, fp16 out) ----
    k_gl<false><<<GLAYER, BT, 0, stream>>>(edges, off, endv, dinv, Ph, W3, b2, Qh,
                                           nullptr, nullptr, nullptr);

    // ---- layer 3 (pipelined fp16 quad gather + b3/relu + FUSED mean-pool) ----
    k_gl<true><<<GLAYER, BT, 0, stream>>>(edges, off, endv, dinv, Qh, nullptr, b3,
                                          nullptr, bat, sums, cnts);

    // ---- head ----
    k_head<<<N_GRAPHS, 64, 0, stream>>>(sums, cnts, Wf1, bf1, Wf2, bf2, out);
}

// Round 21
// 403.655 us; speedup vs baseline: 1.4586x; 1.0058x over previous
//
#include <hip/hip_runtime.h>
#include <hip/hip_fp16.h>

#define N_NODES  200000
#define N_EDGES  3200000
#define HIDDEN   64
#define N_GRAPHS 4096
#define N_CLASSES 7
#define NBUCK    196          // ceil(N_NODES / 1024)
#define BSHIFT   10
#define BMASK    1023
#define BCAP     18432        // fixed bucket capacity (E=16384, sigma~128, 16-sigma margin)
#define CPW      16           // nodes (chunk) per wave
#define NCHUNK   (N_NODES / CPW)          // 12500
#define GLAYER   (NCHUNK / 4)             // 3125 blocks of 4 waves

// ---------- init per-bucket cursors to fixed slot bases ----------
__global__ void k_init(int* __restrict__ gcur) {
    int tid = threadIdx.x;
    if (tid < NBUCK) gcur[tid] = tid * BCAP;
}

// ---------- coarse partition, LDS-staged: block-local counting sort into LDS,
//            then bucket-contiguous (coalesced) global writes into fixed slots ----------
#define PT_EPT 32
#define PT_EDGES (256 * PT_EPT)           // 8192 edges per block
__global__ void k_part(const int* __restrict__ src, const int* __restrict__ dst,
                       int* __restrict__ gcur, int* __restrict__ stage) {
    __shared__ int lh[NBUCK];
    __shared__ int lofs[NBUCK];
    __shared__ int lbase[NBUCK];
    __shared__ int lcur[NBUCK];
    __shared__ int tmp[256];
    __shared__ int buf[PT_EDGES];         // 32 KB staged payloads
    __shared__ unsigned char bid[PT_EDGES];   // bucket id per staged slot
    int tid = threadIdx.x;
    for (int i = tid; i < NBUCK; i += 256) { lh[i] = 0; lcur[i] = 0; }
    __syncthreads();
    int base = blockIdx.x * PT_EDGES + tid;
    for (int k = 0; k < PT_EPT; ++k) {
        int e = base + k * 256;
        if (e < N_EDGES) atomicAdd(&lh[dst[e] >> BSHIFT], 1);
    }
    __syncthreads();
    // block scan of 196 bucket counts -> local offsets; reserve global ranges
    int v = (tid < NBUCK) ? lh[tid] : 0;
    int x = v; tmp[tid] = x; __syncthreads();
    for (int o = 1; o < 256; o <<= 1) {
        int y = (tid >= o) ? tmp[tid - o] : 0;
        __syncthreads();
        x += y; tmp[tid] = x;
        __syncthreads();
    }
    if (tid < NBUCK) {
        lofs[tid] = x - v;
        if (v > 0) lbase[tid] = atomicAdd(&gcur[tid], v);
    }
    __syncthreads();
    // scatter into LDS (cheap) instead of global
    for (int k = 0; k < PT_EPT; ++k) {
        int e = base + k * 256;
        if (e < N_EDGES) {
            int d = dst[e], b = d >> BSHIFT;
            int lp = lofs[b] + atomicAdd(&lcur[b], 1);
            buf[lp] = (src[e] << BSHIFT) | (d & BMASK);
            bid[lp] = (unsigned char)b;
        }
    }
    __syncthreads();
    // bucket-contiguous global writes (runs of ~42 edges -> coalesced)
    int nval = N_EDGES - blockIdx.x * PT_EDGES;
    if (nval > PT_EDGES) nval = PT_EDGES;
    for (int l = tid; l < nval; l += 256) {
        int b = bid[l];
        stage[lbase[b] + (l - lofs[b])] = buf[l];
    }
}

// ---------- per-bucket exact sort + CSR metadata; also prescale x by dinv.
//            ZERO-FILLS the bucket gap so downstream over-reads see valid
//            node index 0 (masked out of sums, but in-bounds). ----------
__global__ void k_sort(const int* __restrict__ stage, const int* __restrict__ gcur,
                       int* __restrict__ edges, int* __restrict__ off,
                       int* __restrict__ endv, float* __restrict__ dinv,
                       const float2* __restrict__ x2, float2* __restrict__ xs2) {
    __shared__ int hist[1024];
    __shared__ int tmp[256];
    int b = blockIdx.x, tid = threadIdx.x;
    int cb0 = b * BCAP;
    int cb1 = gcur[b];                   // cb0 + bucket count
    for (int k = 0; k < 4; ++k) hist[tid * 4 + k] = 0;
    __syncthreads();
    for (int j = cb0 + tid; j < cb1; j += 256)
        atomicAdd(&hist[stage[j] & BMASK], 1);
    __syncthreads();
    int c0 = hist[tid*4], c1 = hist[tid*4+1], c2 = hist[tid*4+2], c3 = hist[tid*4+3];
    int s = c0 + c1 + c2 + c3;
    int x = s; tmp[tid] = x; __syncthreads();
    for (int o = 1; o < 256; o <<= 1) {
        int y = (tid >= o) ? tmp[tid - o] : 0;
        __syncthreads();
        x += y; tmp[tid] = x;
        __syncthreads();
    }
    int run = x - s;                 // exclusive prefix of this thread's 4 counters
    int nbase = b << BSHIFT;
    int counts[4] = {c0, c1, c2, c3};
    for (int k = 0; k < 4; ++k) {
        int v = tid * 4 + k;
        hist[v] = run;               // local cursor start
        int node = nbase + v;
        if (node < N_NODES) {
            off[node]  = cb0 + run;
            endv[node] = cb0 + run + counts[k];
            float di = rsqrtf((float)counts[k] + 1.0f);   // +1 self loop
            dinv[node] = di;
            float2 xv = x2[node];
            xs2[node] = make_float2(di * xv.x, di * xv.y);
        }
        run += counts[k];
    }
    __syncthreads();
    for (int j = cb0 + tid; j < cb1; j += 256) {
        int p = stage[j];
        int pos = atomicAdd(&hist[p & BMASK], 1);
        edges[cb0 + pos] = p >> BSHIFT;     // src
    }
    // zero-fill the gap [cb1, cb0+BCAP) — masked over-reads land on node 0
    for (int j = cb1 + tid; j < cb0 + BCAP; j += 256)
        edges[j] = 0;
}

static __device__ __forceinline__ float rdlf(float v, int l) {
    return __uint_as_float(__builtin_amdgcn_readlane(__float_as_uint(v), (unsigned)l));
}
static __device__ __forceinline__ int rdli(int v, int l) {
    return __builtin_amdgcn_readlane(v, (unsigned)l);
}
// fp16 row fragment (4 channels) -> fp32 accumulate
static __device__ __forceinline__ void acc4h(float4& a, uint2 r) {
    __half2 h01 = *reinterpret_cast<const __half2*>(&r.x);
    __half2 h23 = *reinterpret_cast<const __half2*>(&r.y);
    float2 f01 = __half22float2(h01);
    float2 f23 = __half22float2(h23);
    a.x += f01.x; a.y += f01.y; a.z += f23.x; a.w += f23.y;
}

// ---------- layer 1: chunked gather of prescaled x (value-prefetched) + W1 +
//            relu + fused W2, store fp16 prescaled rows ----------
__global__ __launch_bounds__(256, 4)
void k_l1(const int* __restrict__ edges, const int* __restrict__ off,
          const int* __restrict__ endv, const float* __restrict__ dinv,
          const float2* __restrict__ xs2,
          const float* __restrict__ W1, const float* __restrict__ b1,
          const float* __restrict__ W2, __half* __restrict__ Yout) {
    int lane = threadIdx.x & 63;
    int wid = blockIdx.x * 4 + (threadIdx.x >> 6);
    int n0 = wid * CPW;
    if (n0 >= N_NODES) return;
    float w1a = W1[lane], w1b = W1[64 + lane], bb = b1[lane];
    float4 wc[16];
#pragma unroll
    for (int t = 0; t < 16; ++t) {
        wc[t].x = W2[(4 * t + 0) * 64 + lane];
        wc[t].y = W2[(4 * t + 1) * 64 + lane];
        wc[t].z = W2[(4 * t + 2) * 64 + lane];
        wc[t].w = W2[(4 * t + 3) * 64 + lane];
    }
#pragma unroll
    for (int t = 0; t < 16; ++t) {
        asm volatile("" : "+v"(wc[t].x), "+v"(wc[t].y), "+v"(wc[t].z), "+v"(wc[t].w));
    }
    // chunk metadata in lanes 0..15
    int mo = 0, me = 0; float md = 0.0f; float sxx = 0.0f, sxy = 0.0f;
    if (lane < CPW) {
        int nn = n0 + lane;
        mo = off[nn]; me = endv[nn]; md = dinv[nn];
        float2 sv = xs2[nn];
        sxx = sv.x; sxy = sv.y;
    }
    int j0 = rdli(mo, 0);
    int deg0 = rdli(me, 0) - j0;
    int idx = j0 + lane;
    int ev = edges[idx];
    float pxv = 0.0f, pyv = 0.0f;                // prefetched gather values
    if (lane < deg0) {
        float2 v = xs2[ev];
        pxv = v.x; pyv = v.y;
    }
    for (int i = 0; i < CPW; ++i) {
        int n = n0 + i;
        float dn = rdlf(md, i);
        int deg = rdli(me, i) - j0;
        // prefetch next node's edge vector AND its gather values
        int evn = 0; int j0n = 0;
        float pxn = 0.0f, pyn = 0.0f;
        if (i < CPW - 1) {
            j0n = rdli(mo, i + 1);
            int degn = rdli(me, i + 1) - j0n;
            int idn = j0n + lane;
            evn = edges[idn];
            if (lane < degn) {
                float2 v = xs2[evn];
                pxn = v.x; pyn = v.y;
            }
        }
        float px = pxv, py = pyv;
        for (int jj = j0 + 64 + lane; jj < j0 + deg; jj += 64) {   // rare deg>64 tail
            float2 v = xs2[edges[jj]];
            px += v.x; py += v.y;
        }
#pragma unroll
        for (int o = 1; o < 64; o <<= 1) {
            px += __shfl_xor(px, o, 64);
            py += __shfl_xor(py, o, 64);
        }
        float gx = dn * (px + rdlf(sxx, i));
        float gy = dn * (py + rdlf(sxy, i));
        float h = gx * w1a + gy * w1b + bb;
        h = h > 0.0f ? h : 0.0f;
        float y0 = 0.0f, y1 = 0.0f, y2 = 0.0f, y3 = 0.0f;
#pragma unroll
        for (int t = 0; t < 16; ++t) {
            float4 w = wc[t];
            y0 = fmaf(rdlf(h, 4 * t + 0), w.x, y0);
            y1 = fmaf(rdlf(h, 4 * t + 1), w.y, y1);
            y2 = fmaf(rdlf(h, 4 * t + 2), w.z, y2);
            y3 = fmaf(rdlf(h, 4 * t + 3), w.w, y3);
        }
        Yout[n * 64 + lane] = __float2half(dn * ((y0 + y1) + (y2 + y3)));
        ev = evn; j0 = j0n; pxv = pxn; pyv = pyn;
    }
}

// ---------- layers 2/3: distance-2 pipelined quad-row fp16 gather:
//            edge vectors kept a full iteration ahead (ring of 2), so node
//            i+1's rows issue from a RESIDENT edge vector with no wait.
//            FINAL fuses the mean-pool (batch sorted, atomic run flush). ----------
template<bool FINAL>
__global__ __launch_bounds__(256, 4)
void k_gl(const int* __restrict__ edges, const int* __restrict__ off,
          const int* __restrict__ endv, const float* __restrict__ dinv,
          const __half* __restrict__ Yin, const float* __restrict__ Wn,
          const float* __restrict__ bias, __half* __restrict__ Yout,
          const int* __restrict__ bat, float* __restrict__ sums,
          float* __restrict__ cnts) {
    const uint2* __restrict__ Yin2 = (const uint2*)Yin;   // 16 × 8B per 64-half row
    int lane = threadIdx.x & 63;
    int q = lane & 15, s = lane >> 4;          // sub-group: s = which row of a quad
    int wid = blockIdx.x * 4 + (threadIdx.x >> 6);
    int n0 = wid * CPW;
    if (n0 >= N_NODES) return;
    float bb = bias[lane];
    float4 wc[16];
    if (!FINAL) {
#pragma unroll
        for (int t = 0; t < 16; ++t) {
            wc[t].x = Wn[(4 * t + 0) * 64 + lane];
            wc[t].y = Wn[(4 * t + 1) * 64 + lane];
            wc[t].z = Wn[(4 * t + 2) * 64 + lane];
            wc[t].w = Wn[(4 * t + 3) * 64 + lane];
        }
#pragma unroll
        for (int t = 0; t < 16; ++t) {
            asm volatile("" : "+v"(wc[t].x), "+v"(wc[t].y), "+v"(wc[t].z), "+v"(wc[t].w));
        }
    }
    // chunk metadata in lanes 0..15 (FINAL also loads batch ids)
    int mo = 0, me = 0; float md = 0.0f; int bt = 0;
    if (lane < CPW) {
        int nn = n0 + lane;
        mo = off[nn]; me = endv[nn]; md = dinv[nn];
        if (FINAL) bt = bat[nn];
    }
    // ---- prologue: node 0 (dependent, one-time) + node 1 edge vector ----
    int j0c = rdli(mo, 0);
    int mc = rdli(me, 0) - j0c; if (mc > 64) mc = 64;
    int evc = edges[j0c + lane];                 // edge vector node 0
    int j0n = 0, mn_ = 0, evn = 0;
    {
        j0n = rdli(mo, 1);
        mn_ = rdli(me, 1) - j0n; if (mn_ > 64) mn_ = 64;
        evn = edges[j0n + lane];                 // edge vector node 1 (1 iter early)
    }
    uint2 sraw = make_uint2(0u, 0u);
    uint2 srn  = make_uint2(0u, 0u);
    if (s == 0) {
        sraw = Yin2[(size_t)n0 * 16 + q];        // self row node 0
        srn  = Yin2[(size_t)(n0 + 1) * 16 + q];  // self row node 1
    }
    // rows for node 0 (dependent on evc — unavoidable one-time latency)
    uint2 r0 = make_uint2(0u, 0u), r1 = r0, r2 = r0, r3 = r0;
    uint2 r4 = r0, r5 = r0, r6 = r0, r7 = r0;
    {
        int i0 = __shfl(evc, 0 + s, 64);
        int i1 = __shfl(evc, 4 + s, 64);
        int i2 = __shfl(evc, 8 + s, 64);
        int i3 = __shfl(evc, 12 + s, 64);
        int i4 = __shfl(evc, 16 + s, 64);
        int i5 = __shfl(evc, 20 + s, 64);
        int i6 = __shfl(evc, 24 + s, 64);
        int i7 = __shfl(evc, 28 + s, 64);
        if (mc > 0)  r0 = Yin2[(size_t)i0 * 16 + q];
        if (mc > 4)  r1 = Yin2[(size_t)i1 * 16 + q];
        if (mc > 8)  r2 = Yin2[(size_t)i2 * 16 + q];
        if (mc > 12) r3 = Yin2[(size_t)i3 * 16 + q];
        if (mc > 16) r4 = Yin2[(size_t)i4 * 16 + q];
        if (mc > 20) r5 = Yin2[(size_t)i5 * 16 + q];
        if (mc > 24) r6 = Yin2[(size_t)i6 * 16 + q];
        if (mc > 28) r7 = Yin2[(size_t)i7 * 16 + q];
    }
    // fused-pool running state (FINAL only)
    float accp = 0.0f; int cntp = 0; int gprev = rdli(bt, 0);
    for (int i = 0; i < CPW; ++i) {
        int n = n0 + i;
        float dn = rdlf(md, i);
        int deg = rdli(me, i) - j0c;
        int m = mc;
        // ---- 1. consume self + prefetched first-32 rows (per-lane slot mask) ----
        float4 acc = make_float4(0.f, 0.f, 0.f, 0.f);
        if (s == 0) acc4h(acc, sraw);
        if (0 + s < m)  acc4h(acc, r0);
        if (4 + s < m)  acc4h(acc, r1);
        if (8 + s < m)  acc4h(acc, r2);
        if (12 + s < m) acc4h(acc, r3);
        if (16 + s < m) acc4h(acc, r4);
        if (20 + s < m) acc4h(acc, r5);
        if (24 + s < m) acc4h(acc, r6);
        if (28 + s < m) acc4h(acc, r7);
        // ---- 2. issue node i+1's rows from RESIDENT evn (r* now free) ----
        if (i < CPW - 1) {
            int i0 = __shfl(evn, 0 + s, 64);
            int i1 = __shfl(evn, 4 + s, 64);
            int i2 = __shfl(evn, 8 + s, 64);
            int i3 = __shfl(evn, 12 + s, 64);
            int i4 = __shfl(evn, 16 + s, 64);
            int i5 = __shfl(evn, 20 + s, 64);
            int i6 = __shfl(evn, 24 + s, 64);
            int i7 = __shfl(evn, 28 + s, 64);
            r0 = make_uint2(0u, 0u); r1 = r0; r2 = r0; r3 = r0;
            r4 = r0; r5 = r0; r6 = r0; r7 = r0;
            if (mn_ > 0)  r0 = Yin2[(size_t)i0 * 16 + q];
            if (mn_ > 4)  r1 = Yin2[(size_t)i1 * 16 + q];
            if (mn_ > 8)  r2 = Yin2[(size_t)i2 * 16 + q];
            if (mn_ > 12) r3 = Yin2[(size_t)i3 * 16 + q];
            if (mn_ > 16) r4 = Yin2[(size_t)i4 * 16 + q];
            if (mn_ > 20) r5 = Yin2[(size_t)i5 * 16 + q];
            if (mn_ > 24) r6 = Yin2[(size_t)i6 * 16 + q];
            if (mn_ > 28) r7 = Yin2[(size_t)i7 * 16 + q];
        }
        // ---- 3. load node i+2's edge vector + self row (full-iter cover) ----
        int evn2 = 0, j0n2 = 0, mn2 = 0;
        uint2 srn2 = make_uint2(0u, 0u);
        if (i < CPW - 2) {
            j0n2 = rdli(mo, i + 2);
            mn2 = rdli(me, i + 2) - j0n2; if (mn2 > 64) mn2 = 64;
            evn2 = edges[j0n2 + lane];
            if (s == 0) srn2 = Yin2[(size_t)(n + 2) * 16 + q];
        }
        // ---- 4. remainder 32..m in-line for node i (uses held evc) ----
        for (int t = 8; 4 * t < m; ++t) {
            int sl = 4 * t + s;
            int ii = __shfl(evc, sl, 64);
            uint2 rr = Yin2[(size_t)ii * 16 + q];
            if (sl < m) acc4h(acc, rr);
        }
        // ---- 5. rare deg>64 tail (sub 0 only) ----
        for (int jj = 64; jj < deg; ++jj) {
            int sidx = edges[j0c + jj];
            if (s == 0) {
                uint2 rr = Yin2[(size_t)sidx * 16 + q];
                acc4h(acc, rr);
            }
        }
        // ---- 6. combine the 4 sub-groups (long VALU stretch covers prefetch) ----
        acc.x += __shfl_xor(acc.x, 16, 64); acc.x += __shfl_xor(acc.x, 32, 64);
        acc.y += __shfl_xor(acc.y, 16, 64); acc.y += __shfl_xor(acc.y, 32, 64);
        acc.z += __shfl_xor(acc.z, 16, 64); acc.z += __shfl_xor(acc.z, 32, 64);
        acc.w += __shfl_xor(acc.w, 16, 64); acc.w += __shfl_xor(acc.w, 32, 64);
        // redistribute: channel-per-lane layout
        int srcl = lane >> 2;
        float c0 = __shfl(acc.x, srcl, 64);
        float c1 = __shfl(acc.y, srcl, 64);
        float c2 = __shfl(acc.z, srcl, 64);
        float c3 = __shfl(acc.w, srcl, 64);
        float lo = (lane & 1) ? c1 : c0;
        float hi = (lane & 1) ? c3 : c2;
        float sumc = (lane & 2) ? hi : lo;
        float h = dn * sumc + bb;
        h = h > 0.0f ? h : 0.0f;
        // ---- 7. FINAL fused pool OR transform + store ----
        if (FINAL) {
            int g = rdli(bt, i);
            if (g != gprev) {                    // flush previous graph's run
                atomicAdd(&sums[(size_t)gprev * 64 + lane], accp);
                if (lane == 0) atomicAdd(&cnts[gprev], (float)cntp);
                accp = 0.0f; cntp = 0; gprev = g;
            }
            accp += h; ++cntp;
        } else {
            float y0 = 0.0f, y1 = 0.0f, y2 = 0.0f, y3 = 0.0f;
#pragma unroll
            for (int t2 = 0; t2 < 16; ++t2) {
                float4 w = wc[t2];
                y0 = fmaf(rdlf(h, 4 * t2 + 0), w.x, y0);
                y1 = fmaf(rdlf(h, 4 * t2 + 1), w.y, y1);
                y2 = fmaf(rdlf(h, 4 * t2 + 2), w.z, y2);
                y3 = fmaf(rdlf(h, 4 * t2 + 3), w.w, y3);
            }
            Yout[n * 64 + lane] = __float2half(dn * ((y0 + y1) + (y2 + y3)));
        }
        // ---- 8. rotate the distance-2 pipeline state ----
        evc = evn; evn = evn2;
        j0c = j0n; j0n = j0n2;
        mc = mn_; mn_ = mn2;
        sraw = srn; srn = srn2;
    }
    if (FINAL) {                                 // flush the last run
        atomicAdd(&sums[(size_t)gprev * 64 + lane], accp);
        if (lane == 0) atomicAdd(&cnts[gprev], (float)cntp);
    }
}

// ---------- MLP head ----------
__global__ void k_head(const float* __restrict__ sums, const float* __restrict__ cnts,
                       const float* __restrict__ Wf1, const float* __restrict__ bf1,
                       const float* __restrict__ Wf2, const float* __restrict__ bf2,
                       float* __restrict__ out) {
    __shared__ float p[64];
    __shared__ float h[64];
    int g = blockIdx.x;
    int c = threadIdx.x;
    float cnt = cnts[g];
    cnt = cnt > 1.0f ? cnt : 1.0f;
    p[c] = sums[g * 64 + c] / cnt;
    __syncthreads();
    float s = bf1[c];
#pragma unroll
    for (int k = 0; k < 64; ++k) s += p[k] * Wf1[k * 64 + c];
    h[c] = s > 0.0f ? s : 0.0f;
    __syncthreads();
    if (c < N_CLASSES) {
        float o = bf2[c];
#pragma unroll
        for (int k = 0; k < 64; ++k) o += h[k] * Wf2[k * N_CLASSES + c];
        out[g * N_CLASSES + c] = o;
    }
}

extern "C" void kernel_launch(void* const* d_in, const int* in_sizes, int n_in,
                              void* d_out, int out_size, void* d_ws, size_t ws_size,
                              hipStream_t stream) {
    const float* x   = (const float*)d_in[0];
    const int*   ei  = (const int*)d_in[1];
    const int*   bat = (const int*)d_in[2];
    const float* W1  = (const float*)d_in[3];
    const float* b1  = (const float*)d_in[4];
    const float* W2  = (const float*)d_in[5];
    const float* b2  = (const float*)d_in[6];
    const float* W3  = (const float*)d_in[7];
    const float* b3  = (const float*)d_in[8];
    const float* Wf1 = (const float*)d_in[9];
    const float* bf1 = (const float*)d_in[10];
    const float* Wf2 = (const float*)d_in[11];
    const float* bf2 = (const float*)d_in[12];
    float* out = (float*)d_out;

    const int* src = ei;
    const int* dst = ei + N_EDGES;

    char* p = (char*)d_ws;
    __half* Ph   = (__half*)p;  p += (size_t)N_NODES * 64 * 2;   // fp16 prescaled (post-L1)
    __half* Qh   = (__half*)p;  p += (size_t)N_NODES * 64 * 2;   // fp16 prescaled (post-L2)
    int*   stage = (int*)p;     p += (size_t)NBUCK * BCAP * 4;   // fixed-slot buckets
    int*   edges = (int*)p;     p += (size_t)NBUCK * BCAP * 4;   // gapped CSR payload
    int*   off   = (int*)p;     p += (size_t)N_NODES * 4;
    int*   endv  = (int*)p;     p += (size_t)N_NODES * 4;
    float* dinv  = (float*)p;   p += (size_t)N_NODES * 4;
    float* xs2   = (float*)p;   p += (size_t)N_NODES * 2 * 4;
    int*   gcur  = (int*)p;     p += (size_t)256 * 4;
    float* sums  = (float*)p;   p += (size_t)N_GRAPHS * 64 * 4;
    float* cnts  = (float*)p;   p += (size_t)N_GRAPHS * 4;

    hipMemsetAsync(sums, 0, (size_t)(N_GRAPHS * 64 + N_GRAPHS) * 4, stream);

    const int BT = 256;
    int gPart = (N_EDGES + PT_EDGES - 1) / PT_EDGES;             // 391

    // ---- CSR build (fixed-capacity buckets: no histogram/scan passes) ----
    k_init<<<1, 256, 0, stream>>>(gcur);
    k_part<<<gPart, BT, 0, stream>>>(src, dst, gcur, stage);
    k_sort<<<NBUCK, 256, 0, stream>>>(stage, gcur, edges, off, endv, dinv,
                                      (const float2*)x, (float2*)xs2);

    // ---- layer 1 (pipelined gather x, W1, relu, fused W2 + prescale, fp16 out) ----
    k_l1<<<GLAYER, BT, 0, stream>>>(edges, off, endv, dinv, (const float2*)xs2,
                                    W1, b1, W2, Ph);

    // ---- layer 2 (distance-2 pipelined fp16 gather + b2/relu + fused W3) ----
    k_gl<false><<<GLAYER, BT, 0, stream>>>(edges, off, endv, dinv, Ph, W3, b2, Qh,
                                           nullptr, nullptr, nullptr);

    // ---- layer 3 (distance-2 pipelined fp16 gather + b3/relu + FUSED mean-pool) ----
    k_gl<true><<<GLAYER, BT, 0, stream>>>(edges, off, endv, dinv, Qh, nullptr, b3,
                                          nullptr, bat, sums, cnts);

    // ---- head ----
    k_head<<<N_GRAPHS, 64, 0, stream>>>(sums, cnts, Wf1, bf1, Wf2, bf2, out);
}